// Round 2
// baseline (4621.187 us; speedup 1.0000x reference)
//
#include <hip/hip_runtime.h>
#include <hip/hip_bf16.h>

#define N_SENSORS 325
#define SEQ_T 12
#define DM 128
#define NHEADS 8
#define DFF 512

// ---------------------------------------------------------------------------
// Kernel 0: build CSR for both sparse supports (blockIdx.x selects support).
// Handles duplicate coords by keeping them as separate entries (summed at
// gather time) — segment_sum semantics preserved.
// ---------------------------------------------------------------------------
__global__ __launch_bounds__(256) void build_csr_kernel(
    const float* __restrict__ vals0_in, const int* __restrict__ rows0,
    const int* __restrict__ cols0_in,
    const float* __restrict__ vals1_in, const int* __restrict__ rows1,
    const int* __restrict__ cols1_in, int nnz,
    int* __restrict__ offs, int* __restrict__ out_cols,
    float* __restrict__ out_vals)
{
    const int s = blockIdx.x;
    const float* vals = s ? vals1_in : vals0_in;
    const int*   rows = s ? rows1 : rows0;
    const int*   cols = s ? cols1_in : cols0_in;
    offs     += s * (N_SENSORS + 1);
    out_cols += s * nnz;
    out_vals += s * nnz;

    __shared__ int cnt[N_SENSORS];
    __shared__ int cur[N_SENSORS];
    const int tid = threadIdx.x;
    for (int i = tid; i < N_SENSORS; i += 256) cnt[i] = 0;
    __syncthreads();
    for (int e = tid; e < nnz; e += 256) atomicAdd(&cnt[rows[e]], 1);
    __syncthreads();
    if (tid == 0) {
        int acc = 0;
        for (int i = 0; i < N_SENSORS; ++i) { offs[i] = acc; cur[i] = acc; acc += cnt[i]; }
        offs[N_SENSORS] = acc;
    }
    __syncthreads();
    for (int e = tid; e < nnz; e += 256) {
        int r = rows[e];
        int p = atomicAdd(&cur[r], 1);
        out_cols[p] = cols[e];
        out_vals[p] = vals[e];
    }
}

// ---------------------------------------------------------------------------
// Row mean / rstd over D=128 for 12 rows held in sx; one wave per 3 rows.
// ---------------------------------------------------------------------------
__device__ __forceinline__ void row_stats(const float sx[SEQ_T][DM],
                                          float stats[SEQ_T][2], int tid)
{
    const int w = tid >> 6, lane = tid & 63;
    for (int t = w; t < SEQ_T; t += 4) {
        float a = sx[t][lane], b = sx[t][lane + 64];
        float s = a + b, ss = a * a + b * b;
#pragma unroll
        for (int o = 32; o > 0; o >>= 1) {
            s  += __shfl_down(s, o);
            ss += __shfl_down(ss, o);
        }
        if (lane == 0) {
            float mu  = s * (1.0f / 128.0f);
            float var = ss * (1.0f / 128.0f) - mu * mu;
            stats[t][0] = mu;
            stats[t][1] = rsqrtf(var + 1e-3f);
        }
    }
}

// ---------------------------------------------------------------------------
// Kernel 1: fully fused encoder layer for one bn row (T=12, D=128).
// 256 threads: col = tid&127 (feature / key index), grp = tid>>7 (6 tokens).
// Writes LN2 output to z in (b, t, n, d) layout as bf16.
// ---------------------------------------------------------------------------
__global__ __launch_bounds__(256) void encoder_kernel(
    const float* __restrict__ x,
    const float* __restrict__ Wq, const float* __restrict__ bq,
    const float* __restrict__ Wk, const float* __restrict__ bk,
    const float* __restrict__ Wv, const float* __restrict__ bv,
    const float* __restrict__ Wo, const float* __restrict__ bo,
    const float* __restrict__ ln1g, const float* __restrict__ ln1b,
    const float* __restrict__ W1, const float* __restrict__ b1,
    const float* __restrict__ W2, const float* __restrict__ b2,
    const float* __restrict__ ln2g, const float* __restrict__ ln2b,
    __hip_bfloat16* __restrict__ z)
{
    __shared__ float s_x[SEQ_T][DM];      // current activations (6 KB)
    __shared__ float s_pool[SEQ_T * DFF]; // 24 KB: q|k|v|ctx  OR  h1
    __shared__ float s_attn[SEQ_T][SEQ_T];
    __shared__ float s_stats[SEQ_T][2];

#define S_Q(t, d)   s_pool[(t) * DM + (d)]
#define S_K(t, d)   s_pool[1536 + (t) * DM + (d)]
#define S_V(t, d)   s_pool[3072 + (t) * DM + (d)]
#define S_CTX(t, d) s_pool[4608 + (t) * DM + (d)]
#define S_H1(t, f)  s_pool[(t) * DFF + (f)]

    const int tid = threadIdx.x;
    const int col = tid & 127;
    const int grp = tid >> 7;
    const int t0  = grp * 6;
    const int bn  = blockIdx.x;
    const int b   = bn / N_SENSORS;
    const int n   = bn - b * N_SENSORS;

    // ---- load x (12x128) ----
    const float* xb = x + (size_t)bn * (SEQ_T * DM);
    for (int i = tid; i < SEQ_T * DM; i += 256)
        (&s_x[0][0])[i] = xb[i];
    __syncthreads();

    float accO[6] = {0.f, 0.f, 0.f, 0.f, 0.f, 0.f}; // attn output-proj acc

    // ================= attention heads =================
    for (int h = 0; h < NHEADS; ++h) {
        // ---- q,k,v projection: thread computes (t0..t0+5, col) for head h
        float aq[6] = {0, 0, 0, 0, 0, 0};
        float ak[6] = {0, 0, 0, 0, 0, 0};
        float av[6] = {0, 0, 0, 0, 0, 0};
        const float* wqp = Wq + h * DM + col;  // stride 1024 per d
        const float* wkp = Wk + h * DM + col;
        const float* wvp = Wv + h * DM + col;
        for (int d = 0; d < DM; d += 4) {
            float wq0 = wqp[(d + 0) * 1024], wq1 = wqp[(d + 1) * 1024];
            float wq2 = wqp[(d + 2) * 1024], wq3 = wqp[(d + 3) * 1024];
            float wk0 = wkp[(d + 0) * 1024], wk1 = wkp[(d + 1) * 1024];
            float wk2 = wkp[(d + 2) * 1024], wk3 = wkp[(d + 3) * 1024];
            float wv0 = wvp[(d + 0) * 1024], wv1 = wvp[(d + 1) * 1024];
            float wv2 = wvp[(d + 2) * 1024], wv3 = wvp[(d + 3) * 1024];
#pragma unroll
            for (int j = 0; j < 6; ++j) {
                const float4 xv = *reinterpret_cast<const float4*>(&s_x[t0 + j][d]);
                aq[j] += xv.x * wq0 + xv.y * wq1 + xv.z * wq2 + xv.w * wq3;
                ak[j] += xv.x * wk0 + xv.y * wk1 + xv.z * wk2 + xv.w * wk3;
                av[j] += xv.x * wv0 + xv.y * wv1 + xv.z * wv2 + xv.w * wv3;
            }
        }
        const float bqv = bq[h * DM + col];
        const float bkv = bk[h * DM + col];
        const float bvv = bv[h * DM + col];
#pragma unroll
        for (int j = 0; j < 6; ++j) {
            S_Q(t0 + j, col) = aq[j] + bqv;
            S_K(t0 + j, col) = ak[j] + bkv;
            S_V(t0 + j, col) = av[j] + bvv;
        }
        __syncthreads();

        // ---- scores (12x12) ----
        if (tid < SEQ_T * SEQ_T) {
            const int tt = tid / SEQ_T, ss = tid - tt * SEQ_T;
            float acc = 0.f;
            for (int d = 0; d < DM; d += 4) {
                const float4 qv = *reinterpret_cast<const float4*>(&S_Q(tt, d));
                const float4 kv = *reinterpret_cast<const float4*>(&S_K(ss, d));
                acc += qv.x * kv.x + qv.y * kv.y + qv.z * kv.z + qv.w * kv.w;
            }
            s_attn[tt][ss] = acc * 0.08838834764831845f; // 1/sqrt(128)
        }
        __syncthreads();

        // ---- softmax over s ----
        if (tid < SEQ_T) {
            float m = -1e30f;
#pragma unroll
            for (int s2 = 0; s2 < SEQ_T; ++s2) m = fmaxf(m, s_attn[tid][s2]);
            float e[SEQ_T];
            float sum = 0.f;
#pragma unroll
            for (int s2 = 0; s2 < SEQ_T; ++s2) {
                e[s2] = expf(s_attn[tid][s2] - m);
                sum += e[s2];
            }
            const float inv = 1.0f / sum;
#pragma unroll
            for (int s2 = 0; s2 < SEQ_T; ++s2) s_attn[tid][s2] = e[s2] * inv;
        }
        __syncthreads();

        // ---- ctx = attn @ v ----
#pragma unroll
        for (int j = 0; j < 6; ++j) {
            float c = 0.f;
#pragma unroll
            for (int s2 = 0; s2 < SEQ_T; ++s2)
                c += s_attn[t0 + j][s2] * S_V(s2, col);
            S_CTX(t0 + j, col) = c;
        }
        __syncthreads();

        // ---- out projection accumulate: accO += ctx @ Wo[h] ----
        const float* wop = Wo + h * (DM * DM) + col; // stride 128 per k
        for (int k = 0; k < DM; k += 4) {
            float w0 = wop[(k + 0) * DM], w1 = wop[(k + 1) * DM];
            float w2 = wop[(k + 2) * DM], w3 = wop[(k + 3) * DM];
#pragma unroll
            for (int j = 0; j < 6; ++j) {
                const float4 cv = *reinterpret_cast<const float4*>(&S_CTX(t0 + j, k));
                accO[j] += cv.x * w0 + cv.y * w1 + cv.z * w2 + cv.w * w3;
            }
        }
        __syncthreads(); // before next head overwrites q/k/v
    }

    // ================= residual + LN1 =================
    const float bov = bo[col];
    float r[6];
#pragma unroll
    for (int j = 0; j < 6; ++j) {
        r[j] = s_x[t0 + j][col] + accO[j] + bov;
        s_x[t0 + j][col] = r[j];
    }
    __syncthreads();
    row_stats(s_x, s_stats, tid);
    __syncthreads();
    const float g1 = ln1g[col], be1 = ln1b[col];
#pragma unroll
    for (int j = 0; j < 6; ++j) {
        const float mu = s_stats[t0 + j][0], rs = s_stats[t0 + j][1];
        s_x[t0 + j][col] = (r[j] - mu) * rs * g1 + be1;
    }
    __syncthreads();

    // ================= FFN =================
    // h1: thread handles columns (tid, tid+256) for all 12 tokens.
    {
        float ha[SEQ_T], hb[SEQ_T];
#pragma unroll
        for (int t = 0; t < SEQ_T; ++t) { ha[t] = 0.f; hb[t] = 0.f; }
        for (int d = 0; d < DM; d += 2) {
            const float w1a0 = W1[(d + 0) * DFF + tid];
            const float w1a1 = W1[(d + 1) * DFF + tid];
            const float w1b0 = W1[(d + 0) * DFF + tid + 256];
            const float w1b1 = W1[(d + 1) * DFF + tid + 256];
#pragma unroll
            for (int t = 0; t < SEQ_T; ++t) {
                const float2 xv = *reinterpret_cast<const float2*>(&s_x[t][d]);
                ha[t] += xv.x * w1a0 + xv.y * w1a1;
                hb[t] += xv.x * w1b0 + xv.y * w1b1;
            }
        }
        const float b1a = b1[tid], b1b = b1[tid + 256];
        __syncthreads(); // pool (q/k/v/ctx) no longer needed; reuse as h1
#pragma unroll
        for (int t = 0; t < SEQ_T; ++t) {
            S_H1(t, tid)       = fmaxf(ha[t] + b1a, 0.f);
            S_H1(t, tid + 256) = fmaxf(hb[t] + b1b, 0.f);
        }
    }
    __syncthreads();

    // h2 + residual + LN2
    float acc2[6] = {0.f, 0.f, 0.f, 0.f, 0.f, 0.f};
    for (int f = 0; f < DFF; f += 4) {
        const float w20 = W2[(f + 0) * DM + col];
        const float w21 = W2[(f + 1) * DM + col];
        const float w22 = W2[(f + 2) * DM + col];
        const float w23 = W2[(f + 3) * DM + col];
#pragma unroll
        for (int j = 0; j < 6; ++j) {
            const float4 hv = *reinterpret_cast<const float4*>(&S_H1(t0 + j, f));
            acc2[j] += hv.x * w20 + hv.y * w21 + hv.z * w22 + hv.w * w23;
        }
    }
    const float b2v = b2[col];
    float r2[6];
#pragma unroll
    for (int j = 0; j < 6; ++j) {
        r2[j] = s_x[t0 + j][col] + acc2[j] + b2v;
    }
    __syncthreads();
#pragma unroll
    for (int j = 0; j < 6; ++j) s_x[t0 + j][col] = r2[j];
    __syncthreads();
    row_stats(s_x, s_stats, tid);
    __syncthreads();
    const float g2 = ln2g[col], be2 = ln2b[col];
#pragma unroll
    for (int j = 0; j < 6; ++j) {
        const int t = t0 + j;
        const float mu = s_stats[t][0], rs = s_stats[t][1];
        const float y = (r2[j] - mu) * rs * g2 + be2;
        // z layout: ((b*12 + t)*325 + n)*128 + col
        z[(((size_t)b * SEQ_T + t) * N_SENSORS + n) * DM + col] = __float2bfloat16(y);
    }
#undef S_Q
#undef S_K
#undef S_V
#undef S_CTX
#undef S_H1
}

// ---------------------------------------------------------------------------
// Kernel 2: fused MGCN: per (bt, 32-row chunk): gather X0 rows, spmm X1/X2
// rows via CSR, then [X0 X1 X2] @ gc_kernel + bias -> d_out (rearranged).
// ---------------------------------------------------------------------------
__global__ __launch_bounds__(256) void mgcn_kernel(
    const __hip_bfloat16* __restrict__ z,
    const int* __restrict__ offs0, const int* __restrict__ cols0,
    const float* __restrict__ vals0,
    const int* __restrict__ offs1, const int* __restrict__ cols1,
    const float* __restrict__ vals1,
    const float* __restrict__ gc, const float* __restrict__ gcb,
    float* __restrict__ out)
{
    __shared__ float s_in[32][3 * DM]; // 48 KB
    const int bt    = blockIdx.x;        // b*12 + t
    const int chunk = blockIdx.y;
    const int n0    = chunk * 32;
    const int b     = bt / SEQ_T;
    const int t     = bt - b * SEQ_T;
    const int tid   = threadIdx.x;

    const __hip_bfloat16* zbt = z + (size_t)bt * (N_SENSORS * DM);

    // ---- X0 rows ----
    for (int i = tid; i < 32 * DM; i += 256) {
        const int rr = i >> 7, d = i & 127;
        const int nn = n0 + rr;
        s_in[rr][d] = (nn < N_SENSORS) ? __bfloat162float(zbt[nn * DM + d]) : 0.f;
    }
    // ---- X1/X2 rows via CSR gather (wave per row) ----
    const int w = tid >> 6, lane = tid & 63;
    for (int s = 0; s < 2; ++s) {
        const int*   offs  = s ? offs1 : offs0;
        const int*   ccols = s ? cols1 : cols0;
        const float* cvals = s ? vals1 : vals0;
        for (int rr = w; rr < 32; rr += 4) {
            const int nn = n0 + rr;
            float a0 = 0.f, a1 = 0.f;
            if (nn < N_SENSORS) {
                const int e0 = offs[nn], e1 = offs[nn + 1];
                for (int e = e0; e < e1; ++e) {
                    const float vv = cvals[e];
                    const __hip_bfloat16* zr = zbt + ccols[e] * DM;
                    a0 += vv * __bfloat162float(zr[lane]);
                    a1 += vv * __bfloat162float(zr[lane + 64]);
                }
            }
            s_in[rr][(s + 1) * DM + lane]      = a0;
            s_in[rr][(s + 1) * DM + lane + 64] = a1;
        }
    }
    __syncthreads();

    // ---- GEMM: (32 x 384) @ (384 x 128) ----
    const int dout = tid & 127, rg = tid >> 7; // rg: rows rg*16 .. rg*16+15
    float acc[16];
#pragma unroll
    for (int rr = 0; rr < 16; ++rr) acc[rr] = 0.f;
    for (int m = 0; m < 3; ++m) {
        for (int d = 0; d < DM; d += 4) {
            // gc row index for (m, d) is d*3 + m
            const float g0 = gc[((d + 0) * 3 + m) * DM + dout];
            const float g1 = gc[((d + 1) * 3 + m) * DM + dout];
            const float g2 = gc[((d + 2) * 3 + m) * DM + dout];
            const float g3 = gc[((d + 3) * 3 + m) * DM + dout];
#pragma unroll
            for (int rr = 0; rr < 16; ++rr) {
                const float4 iv =
                    *reinterpret_cast<const float4*>(&s_in[rg * 16 + rr][m * DM + d]);
                acc[rr] += iv.x * g0 + iv.y * g1 + iv.z * g2 + iv.w * g3;
            }
        }
    }
    const float bias = gcb[dout];
#pragma unroll
    for (int rr = 0; rr < 16; ++rr) {
        const int nn = n0 + rg * 16 + rr;
        if (nn < N_SENSORS) {
            // out layout: ((b*325 + n)*12 + t)*128 + dout
            out[(((size_t)b * N_SENSORS + nn) * SEQ_T + t) * DM + dout] = acc[rr] + bias;
        }
    }
}

// ---------------------------------------------------------------------------
extern "C" void kernel_launch(void* const* d_in, const int* in_sizes, int n_in,
                              void* d_out, int out_size, void* d_ws, size_t ws_size,
                              hipStream_t stream)
{
    const float* x    = (const float*)d_in[0];
    const float* Wq   = (const float*)d_in[1];
    const float* bq   = (const float*)d_in[2];
    const float* Wk   = (const float*)d_in[3];
    const float* bk   = (const float*)d_in[4];
    const float* Wv   = (const float*)d_in[5];
    const float* bv   = (const float*)d_in[6];
    const float* Wo   = (const float*)d_in[7];
    const float* bo   = (const float*)d_in[8];
    const float* ln1g = (const float*)d_in[9];
    const float* ln1b = (const float*)d_in[10];
    const float* W1   = (const float*)d_in[11];
    const float* b1   = (const float*)d_in[12];
    const float* W2   = (const float*)d_in[13];
    const float* b2   = (const float*)d_in[14];
    const float* ln2g = (const float*)d_in[15];
    const float* ln2b = (const float*)d_in[16];
    const float* gc   = (const float*)d_in[17];
    const float* gcb  = (const float*)d_in[18];
    const float* s0v  = (const float*)d_in[19];
    const float* s1v  = (const float*)d_in[20];
    const int*   s0r  = (const int*)d_in[21];
    const int*   s0c  = (const int*)d_in[22];
    const int*   s1r  = (const int*)d_in[23];
    const int*   s1c  = (const int*)d_in[24];
    const int nnz = in_sizes[19];

    const int BN = in_sizes[0] / (SEQ_T * DM);
    const int B  = BN / N_SENSORS;

    char* ws = (char*)d_ws;
    __hip_bfloat16* z = (__hip_bfloat16*)ws;
    size_t zbytes = (size_t)BN * SEQ_T * DM * sizeof(__hip_bfloat16);
    size_t off = (zbytes + 255) & ~(size_t)255;
    int*   offs = (int*)(ws + off);                 // 2 * (N_SENSORS+1)
    int*   csr_cols = offs + 2 * (N_SENSORS + 1);   // 2 * nnz
    float* csr_vals = (float*)(csr_cols + 2 * nnz); // 2 * nnz

    hipLaunchKernelGGL(build_csr_kernel, dim3(2), dim3(256), 0, stream,
                       s0v, s0r, s0c, s1v, s1r, s1c, nnz,
                       offs, csr_cols, csr_vals);
    hipLaunchKernelGGL(encoder_kernel, dim3(BN), dim3(256), 0, stream,
                       x, Wq, bq, Wk, bk, Wv, bv, Wo, bo, ln1g, ln1b,
                       W1, b1, W2, b2, ln2g, ln2b, z);
    hipLaunchKernelGGL(mgcn_kernel, dim3(B * SEQ_T, (N_SENSORS + 31) / 32), dim3(256),
                       0, stream, z,
                       offs, csr_cols, csr_vals,
                       offs + (N_SENSORS + 1), csr_cols + nnz, csr_vals + nnz,
                       gc, gcb, (float*)d_out);
}

// Round 3
// 1796.836 us; speedup vs baseline: 2.5718x; 2.5718x over previous
//
#include <hip/hip_runtime.h>
#include <hip/hip_bf16.h>

#define N_SENSORS 325
#define SEQ_T 12
#define DM 128
#define NHEADS 8
#define DFF 512

typedef __attribute__((ext_vector_type(8))) short bf16x8;
typedef __attribute__((ext_vector_type(4))) float f32x4;

__device__ __forceinline__ float bfbits2f(short s) {
    return __uint_as_float(((unsigned)(unsigned short)s) << 16);
}
__device__ __forceinline__ void gload_lds16(const void* g, void* l) {
    __builtin_amdgcn_global_load_lds((const __attribute__((address_space(1))) void*)g,
                                     (__attribute__((address_space(3))) void*)l, 16, 0, 0);
}

// ---------------------------------------------------------------------------
// CSR build for both sparse supports (blockIdx.x selects support).
// ---------------------------------------------------------------------------
__global__ __launch_bounds__(256) void build_csr_kernel(
    const float* __restrict__ vals0_in, const int* __restrict__ rows0,
    const int* __restrict__ cols0_in,
    const float* __restrict__ vals1_in, const int* __restrict__ rows1,
    const int* __restrict__ cols1_in, int nnz,
    int* __restrict__ offs, int* __restrict__ out_cols,
    float* __restrict__ out_vals)
{
    const int s = blockIdx.x;
    const float* vals = s ? vals1_in : vals0_in;
    const int*   rows = s ? rows1 : rows0;
    const int*   cols = s ? cols1_in : cols0_in;
    offs     += s * (N_SENSORS + 1);
    out_cols += s * nnz;
    out_vals += s * nnz;

    __shared__ int cnt[N_SENSORS];
    __shared__ int cur[N_SENSORS];
    const int tid = threadIdx.x;
    for (int i = tid; i < N_SENSORS; i += 256) cnt[i] = 0;
    __syncthreads();
    for (int e = tid; e < nnz; e += 256) atomicAdd(&cnt[rows[e]], 1);
    __syncthreads();
    if (tid == 0) {
        int acc = 0;
        for (int i = 0; i < N_SENSORS; ++i) { offs[i] = acc; cur[i] = acc; acc += cnt[i]; }
        offs[N_SENSORS] = acc;
    }
    __syncthreads();
    for (int e = tid; e < nnz; e += 256) {
        int r = rows[e];
        int p = atomicAdd(&cur[r], 1);
        out_cols[p] = cols[e];
        out_vals[p] = vals[e];
    }
}

// ---------------------------------------------------------------------------
// Weight prep: transpose + cast to bf16, [n][k] layout (k contiguous).
//   Wqkv_t[3072][128] : n = qkv*1024 + h*128 + kk, k = d
//   Wo_t  [128][1024] : n = d_out, k = h*128 + kk
//   W1_t  [512][128]  : n = f, k = d
//   W2_t  [128][512]  : n = d_out, k = f
// ---------------------------------------------------------------------------
__global__ __launch_bounds__(256) void prep_weights_kernel(
    const float* __restrict__ Wq, const float* __restrict__ Wk,
    const float* __restrict__ Wv, const float* __restrict__ Wo,
    const float* __restrict__ W1, const float* __restrict__ W2,
    __hip_bfloat16* __restrict__ Wqkv_t, __hip_bfloat16* __restrict__ Wo_t,
    __hip_bfloat16* __restrict__ W1_t, __hip_bfloat16* __restrict__ W2_t)
{
    int id = blockIdx.x * 256 + threadIdx.x;  // exact grid: 655360
    if (id < 393216) {
        int k = id & 127, n = id >> 7;
        int kk = n & 127, h = (n >> 7) & 7, sel = n >> 10;
        const float* W = sel == 0 ? Wq : (sel == 1 ? Wk : Wv);
        Wqkv_t[id] = __float2bfloat16(W[(k * 8 + h) * 128 + kk]);
    } else if (id < 524288) {
        int t = id - 393216;
        int d = t >> 10, r = t & 1023, h = r >> 7, kk = r & 127;
        Wo_t[t] = __float2bfloat16(Wo[(h * 128 + kk) * 128 + d]);
    } else if (id < 589824) {
        int t = id - 524288;
        int f = t >> 7, d = t & 127;
        W1_t[t] = __float2bfloat16(W1[d * 512 + f]);
    } else {
        int t = id - 589824;
        int d = t >> 9, f = t & 511;
        W2_t[t] = __float2bfloat16(W2[f * 128 + d]);
    }
}

__global__ __launch_bounds__(256) void cast_x_kernel(
    const float* __restrict__ x, __hip_bfloat16* __restrict__ out, int n8)
{
    int i = blockIdx.x * 256 + threadIdx.x;
    if (i >= n8) return;
    const float4* src = (const float4*)(x + (size_t)i * 8);
    float4 a = src[0], b = src[1];
    union { unsigned short us[8]; float4 f4; } r;
    __hip_bfloat16 h;
    h = __float2bfloat16(a.x); r.us[0] = *(unsigned short*)&h;
    h = __float2bfloat16(a.y); r.us[1] = *(unsigned short*)&h;
    h = __float2bfloat16(a.z); r.us[2] = *(unsigned short*)&h;
    h = __float2bfloat16(a.w); r.us[3] = *(unsigned short*)&h;
    h = __float2bfloat16(b.x); r.us[4] = *(unsigned short*)&h;
    h = __float2bfloat16(b.y); r.us[5] = *(unsigned short*)&h;
    h = __float2bfloat16(b.z); r.us[6] = *(unsigned short*)&h;
    h = __float2bfloat16(b.w); r.us[7] = *(unsigned short*)&h;
    *(float4*)(out + (size_t)i * 8) = r.f4;
}

// ---------------------------------------------------------------------------
// MFMA GEMM, 128x128 tile, 4 waves (wave tile 32x128), K in 128-chunks.
// A[m][k] bf16 (stride Astride elems), B[n][k] bf16 (stride Bstride).
// Staging: global_load_lds 16B, XOR-swizzled source (slot ^= row&7), swizzled
// ds_read_b128 on the frag reads (both-sides rule).
// EPI: 0=QKV(+bias), 1=outproj(+bo+resid_f32+LN1), 2=FFN1(+b1,relu),
//      3=FFN2(+b2+resid_bf16+LN2, scatter to z layout).
// ---------------------------------------------------------------------------
template <int EPI>
__global__ __launch_bounds__(256) void gemm_kernel(
    const __hip_bfloat16* __restrict__ A, int Astride,
    const __hip_bfloat16* __restrict__ Bw, int Bstride,
    int Ktot,
    __hip_bfloat16* __restrict__ C, int Cstride,
    int m0base,
    const float* __restrict__ bias0, const float* __restrict__ bias1,
    const float* __restrict__ bias2,
    const float* __restrict__ resid_f32,
    const __hip_bfloat16* __restrict__ resid_bf,
    const float* __restrict__ ln_g, const float* __restrict__ ln_b)
{
    __shared__ __hip_bfloat16 Alds[128 * 128];
    __shared__ __hip_bfloat16 Blds[128 * 128];
    const int tid  = threadIdx.x;
    const int w    = tid >> 6, lane = tid & 63;
    const int l15  = lane & 15, g4 = lane >> 4;
    const int m0   = blockIdx.x * 128;
    const int n0   = blockIdx.y * 128;

    f32x4 acc[2][8];
#pragma unroll
    for (int a = 0; a < 2; ++a)
#pragma unroll
        for (int b = 0; b < 8; ++b) acc[a][b] = (f32x4){0.f, 0.f, 0.f, 0.f};

    const int nchunks = Ktot >> 7;
    for (int kc = 0; kc < nchunks; ++kc) {
#pragma unroll
        for (int i = 0; i < 8; ++i) {
            int fs = (w * 8 + i) * 64 + lane;
            int row = fs >> 4, slot = fs & 15;
            int sw = (slot ^ (row & 7)) << 4;
            gload_lds16((const char*)A + ((size_t)(m0 + row) * Astride + (size_t)kc * 128) * 2 + sw,
                        (char*)Alds + (size_t)(w * 8 + i) * 1024);
            gload_lds16((const char*)Bw + ((size_t)(n0 + row) * Bstride + (size_t)kc * 128) * 2 + sw,
                        (char*)Blds + (size_t)(w * 8 + i) * 1024);
        }
        __syncthreads();
        const char* Ab = (const char*)Alds;
        const char* Bb = (const char*)Blds;
#pragma unroll
        for (int ks = 0; ks < 4; ++ks) {
            bf16x8 af[2], bfr[8];
#pragma unroll
            for (int fm = 0; fm < 2; ++fm) {
                int row = w * 32 + fm * 16 + l15;
                int c = (ks * 4 + g4) ^ (row & 7);
                af[fm] = *(const bf16x8*)(Ab + row * 256 + c * 16);
            }
#pragma unroll
            for (int fn = 0; fn < 8; ++fn) {
                int row = fn * 16 + l15;
                int c = (ks * 4 + g4) ^ (row & 7);
                bfr[fn] = *(const bf16x8*)(Bb + row * 256 + c * 16);
            }
#pragma unroll
            for (int fm = 0; fm < 2; ++fm)
#pragma unroll
                for (int fn = 0; fn < 8; ++fn)
                    acc[fm][fn] = __builtin_amdgcn_mfma_f32_16x16x32_bf16(
                        af[fm], bfr[fn], acc[fm][fn], 0, 0, 0);
        }
        __syncthreads();
    }

    // ---- epilogue: stage bf16 C tile in Alds (reuse), then coalesced write
    __hip_bfloat16* Clds = (__hip_bfloat16*)Alds;
    if (EPI == 0 || EPI == 2) {
#pragma unroll
        for (int fm = 0; fm < 2; ++fm)
#pragma unroll
            for (int reg = 0; reg < 4; ++reg) {
                int mlt = w * 32 + fm * 16 + g4 * 4 + reg;
#pragma unroll
                for (int fn = 0; fn < 8; ++fn) {
                    int nl = fn * 16 + l15;
                    int n_g = n0 + nl;
                    float bias;
                    if (EPI == 0) {
                        const float* bp = n_g < 1024 ? bias0 : (n_g < 2048 ? bias1 : bias2);
                        bias = bp[n_g & 1023];
                    } else {
                        bias = bias0[n_g];
                    }
                    float v = acc[fm][fn][reg] + bias;
                    if (EPI == 2) v = fmaxf(v, 0.f);
                    Clds[mlt * 128 + nl] = __float2bfloat16(v);
                }
            }
    } else {
#pragma unroll
        for (int fm = 0; fm < 2; ++fm)
#pragma unroll
            for (int reg = 0; reg < 4; ++reg) {
                int mlt = w * 32 + fm * 16 + g4 * 4 + reg;
                int m_g = m0base + m0 + mlt;
                float v[8], s1 = 0.f, s2 = 0.f;
#pragma unroll
                for (int fn = 0; fn < 8; ++fn) {
                    int nl = fn * 16 + l15;
                    float t = acc[fm][fn][reg] + bias0[nl];
                    if (EPI == 1) t += resid_f32[(size_t)m_g * 128 + nl];
                    else          t += bfbits2f(((const short*)resid_bf)[(size_t)(m0 + mlt) * 128 + nl]);
                    v[fn] = t; s1 += t; s2 += t * t;
                }
#pragma unroll
                for (int o = 1; o < 16; o <<= 1) {
                    s1 += __shfl_xor(s1, o);
                    s2 += __shfl_xor(s2, o);
                }
                float mu = s1 * (1.f / 128.f);
                float rstd = rsqrtf(s2 * (1.f / 128.f) - mu * mu + 1e-3f);
#pragma unroll
                for (int fn = 0; fn < 8; ++fn) {
                    int nl = fn * 16 + l15;
                    float o = (v[fn] - mu) * rstd * ln_g[nl] + ln_b[nl];
                    Clds[mlt * 128 + nl] = __float2bfloat16(o);
                }
            }
    }
    __syncthreads();
#pragma unroll
    for (int i = 0; i < 8; ++i) {
        int fs = i * 256 + tid;
        int row = fs >> 4, slot = fs & 15;
        float4 val = *(const float4*)((const char*)Alds + (size_t)fs * 16);
        if (EPI == 3) {
            int m_g = m0base + m0 + row;
            int bn = m_g / 12, t = m_g - bn * 12;
            int b = bn / N_SENSORS, ns = bn - b * N_SENSORS;
            *(float4*)((char*)C + ((size_t)((b * 12 + t) * N_SENSORS + ns) * 128) * 2 + slot * 16) = val;
        } else {
            *(float4*)((char*)C + ((size_t)(m0 + row) * Cstride + n0) * 2 + slot * 16) = val;
        }
    }
}

// ---------------------------------------------------------------------------
// Attention core (VALU f32): per bn, reads its 12 rows of QKV (stripe-local),
// computes softmax(QK^T/sqrt(128))V per head, writes ctx in-place into the
// q-columns (cols 0..1023) of the same buffer.
// ---------------------------------------------------------------------------
__global__ __launch_bounds__(256) void attn_kernel(__hip_bfloat16* __restrict__ QKV)
{
    __shared__ __hip_bfloat16 s_qkv[SEQ_T * 3072];  // 72 KB
    __shared__ float s_S[NHEADS][SEQ_T][SEQ_T];
    const int tid = threadIdx.x;
    const int row0 = blockIdx.x * SEQ_T;

    const float4* src = (const float4*)(QKV + (size_t)row0 * 3072);
    float4* dst = (float4*)s_qkv;
#pragma unroll
    for (int i = 0; i < 18; ++i) dst[i * 256 + tid] = src[i * 256 + tid];
    __syncthreads();

    for (int it = tid; it < NHEADS * SEQ_T * SEQ_T; it += 256) {
        int h = it / 144, r = it - h * 144;
        int t = r / 12, s = r - t * 12;
        const bf16x8* qp = (const bf16x8*)(s_qkv + t * 3072 + h * 128);
        const bf16x8* kp = (const bf16x8*)(s_qkv + s * 3072 + 1024 + h * 128);
        float acc = 0.f;
#pragma unroll
        for (int dd = 0; dd < 16; ++dd) {
            bf16x8 qv = qp[dd], kv = kp[dd];
#pragma unroll
            for (int j = 0; j < 8; ++j) acc += bfbits2f(qv[j]) * bfbits2f(kv[j]);
        }
        s_S[h][t][s] = acc * 0.08838834764831845f;
    }
    __syncthreads();

    if (tid < NHEADS * SEQ_T) {
        int h = tid / 12, t = tid - h * 12;
        float m = -1e30f;
#pragma unroll
        for (int s = 0; s < 12; ++s) m = fmaxf(m, s_S[h][t][s]);
        float e[12], sum = 0.f;
#pragma unroll
        for (int s = 0; s < 12; ++s) { e[s] = expf(s_S[h][t][s] - m); sum += e[s]; }
        float inv = 1.f / sum;
#pragma unroll
        for (int s = 0; s < 12; ++s) s_S[h][t][s] = e[s] * inv;
    }
    __syncthreads();

#pragma unroll 4
    for (int j = 0; j < 48; ++j) {
        int it = j * 256 + tid;
        int t = it >> 10, n = it & 1023;
        int h = n >> 7, kk = n & 127;
        float c = 0.f;
#pragma unroll
        for (int s = 0; s < 12; ++s)
            c += s_S[h][t][s] * bfbits2f(((const short*)s_qkv)[s * 3072 + 2048 + h * 128 + kk]);
        QKV[(size_t)(row0 + t) * 3072 + n] = __float2bfloat16(c);
    }
}

// ---------------------------------------------------------------------------
// MGCN (unchanged from round 2 — passed).
// ---------------------------------------------------------------------------
__global__ __launch_bounds__(256) void mgcn_kernel(
    const __hip_bfloat16* __restrict__ z,
    const int* __restrict__ offs0, const int* __restrict__ cols0,
    const float* __restrict__ vals0,
    const int* __restrict__ offs1, const int* __restrict__ cols1,
    const float* __restrict__ vals1,
    const float* __restrict__ gc, const float* __restrict__ gcb,
    float* __restrict__ out)
{
    __shared__ float s_in[32][3 * DM];
    const int bt    = blockIdx.x;
    const int chunk = blockIdx.y;
    const int n0    = chunk * 32;
    const int b     = bt / SEQ_T;
    const int t     = bt - b * SEQ_T;
    const int tid   = threadIdx.x;

    const __hip_bfloat16* zbt = z + (size_t)bt * (N_SENSORS * DM);

    for (int i = tid; i < 32 * DM; i += 256) {
        const int rr = i >> 7, d = i & 127;
        const int nn = n0 + rr;
        s_in[rr][d] = (nn < N_SENSORS) ? __bfloat162float(zbt[nn * DM + d]) : 0.f;
    }
    const int w = tid >> 6, lane = tid & 63;
    for (int s = 0; s < 2; ++s) {
        const int*   offs  = s ? offs1 : offs0;
        const int*   ccols = s ? cols1 : cols0;
        const float* cvals = s ? vals1 : vals0;
        for (int rr = w; rr < 32; rr += 4) {
            const int nn = n0 + rr;
            float a0 = 0.f, a1 = 0.f;
            if (nn < N_SENSORS) {
                const int e0 = offs[nn], e1 = offs[nn + 1];
                for (int e = e0; e < e1; ++e) {
                    const float vv = cvals[e];
                    const __hip_bfloat16* zr = zbt + ccols[e] * DM;
                    a0 += vv * __bfloat162float(zr[lane]);
                    a1 += vv * __bfloat162float(zr[lane + 64]);
                }
            }
            s_in[rr][(s + 1) * DM + lane]      = a0;
            s_in[rr][(s + 1) * DM + lane + 64] = a1;
        }
    }
    __syncthreads();

    const int dout = tid & 127, rg = tid >> 7;
    float acc[16];
#pragma unroll
    for (int rr = 0; rr < 16; ++rr) acc[rr] = 0.f;
    for (int m = 0; m < 3; ++m) {
        for (int d = 0; d < DM; d += 4) {
            const float g0 = gc[((d + 0) * 3 + m) * DM + dout];
            const float g1 = gc[((d + 1) * 3 + m) * DM + dout];
            const float g2 = gc[((d + 2) * 3 + m) * DM + dout];
            const float g3 = gc[((d + 3) * 3 + m) * DM + dout];
#pragma unroll
            for (int rr = 0; rr < 16; ++rr) {
                const float4 iv =
                    *reinterpret_cast<const float4*>(&s_in[rg * 16 + rr][m * DM + d]);
                acc[rr] += iv.x * g0 + iv.y * g1 + iv.z * g2 + iv.w * g3;
            }
        }
    }
    const float bias = gcb[dout];
#pragma unroll
    for (int rr = 0; rr < 16; ++rr) {
        const int nn = n0 + rg * 16 + rr;
        if (nn < N_SENSORS) {
            out[(((size_t)b * N_SENSORS + nn) * SEQ_T + t) * DM + dout] = acc[rr] + bias;
        }
    }
}

// ---------------------------------------------------------------------------
extern "C" void kernel_launch(void* const* d_in, const int* in_sizes, int n_in,
                              void* d_out, int out_size, void* d_ws, size_t ws_size,
                              hipStream_t stream)
{
    const float* x    = (const float*)d_in[0];
    const float* Wq   = (const float*)d_in[1];
    const float* bq   = (const float*)d_in[2];
    const float* Wk   = (const float*)d_in[3];
    const float* bk   = (const float*)d_in[4];
    const float* Wv   = (const float*)d_in[5];
    const float* bv   = (const float*)d_in[6];
    const float* Wo   = (const float*)d_in[7];
    const float* bo   = (const float*)d_in[8];
    const float* ln1g = (const float*)d_in[9];
    const float* ln1b = (const float*)d_in[10];
    const float* W1   = (const float*)d_in[11];
    const float* b1   = (const float*)d_in[12];
    const float* W2   = (const float*)d_in[13];
    const float* b2   = (const float*)d_in[14];
    const float* ln2g = (const float*)d_in[15];
    const float* ln2b = (const float*)d_in[16];
    const float* gc   = (const float*)d_in[17];
    const float* gcb  = (const float*)d_in[18];
    const float* s0v  = (const float*)d_in[19];
    const float* s1v  = (const float*)d_in[20];
    const int*   s0r  = (const int*)d_in[21];
    const int*   s0c  = (const int*)d_in[22];
    const int*   s1r  = (const int*)d_in[23];
    const int*   s1c  = (const int*)d_in[24];
    const int nnz  = in_sizes[19];
    const int BN   = in_sizes[0] / (SEQ_T * DM);   // 10400
    const int Bsz  = BN / N_SENSORS;               // 32
    const int Mtot = BN * SEQ_T;                   // 124800
    const int ngroups = Mtot / 384;                // 325 (32 bn per group)

    char* ws = (char*)d_ws;
    size_t off = 0;
    auto alloc = [&](size_t bytes) {
        char* r = ws + off;
        off = (off + bytes + 255) & ~(size_t)255;
        return r;
    };

    __hip_bfloat16* z      = (__hip_bfloat16*)alloc((size_t)Mtot * DM * 2);
    int*            offs   = (int*)alloc((size_t)2 * (N_SENSORS + 1) * 4);
    int*            ccols  = (int*)alloc((size_t)2 * nnz * 4);
    float*          cvals  = (float*)alloc((size_t)2 * nnz * 4);
    __hip_bfloat16* Xbf    = (__hip_bfloat16*)alloc((size_t)Mtot * DM * 2);
    __hip_bfloat16* Wqkv_t = (__hip_bfloat16*)alloc((size_t)3072 * 128 * 2);
    __hip_bfloat16* Wo_t   = (__hip_bfloat16*)alloc((size_t)128 * 1024 * 2);
    __hip_bfloat16* W1_t   = (__hip_bfloat16*)alloc((size_t)512 * 128 * 2);
    __hip_bfloat16* W2_t   = (__hip_bfloat16*)alloc((size_t)128 * 512 * 2);

    const size_t PER_GROUP = (size_t)384 * (3072 + 512 + 128) * 2 + 1024;
    size_t avail = (ws_size > off) ? (ws_size - off) : 0;
    int g = (int)(avail / PER_GROUP);
    if (g < 1) g = 1;
    if (g > ngroups) g = ngroups;
    __hip_bfloat16* qkvbuf = (__hip_bfloat16*)alloc((size_t)384 * g * 3072 * 2);
    __hip_bfloat16* h1buf  = (__hip_bfloat16*)alloc((size_t)384 * g * 512 * 2);
    __hip_bfloat16* y1buf  = (__hip_bfloat16*)alloc((size_t)384 * g * 128 * 2);

    hipLaunchKernelGGL(prep_weights_kernel, dim3(2560), dim3(256), 0, stream,
                       Wq, Wk, Wv, Wo, W1, W2, Wqkv_t, Wo_t, W1_t, W2_t);
    int total8 = Mtot * DM / 8;
    hipLaunchKernelGGL(cast_x_kernel, dim3((total8 + 255) / 256), dim3(256), 0, stream,
                       x, Xbf, total8);
    hipLaunchKernelGGL(build_csr_kernel, dim3(2), dim3(256), 0, stream,
                       s0v, s0r, s0c, s1v, s1r, s1c, nnz, offs, ccols, cvals);

    for (int s = 0; s < ngroups; s += g) {
        int gs = (g < ngroups - s) ? g : (ngroups - s);
        int rows = 384 * gs;
        int m0base = 384 * s;
        // QKV projection: [rows x 128] @ [128 x 3072] + bias -> qkvbuf
        hipLaunchKernelGGL(HIP_KERNEL_NAME(gemm_kernel<0>), dim3(rows / 128, 24), dim3(256), 0, stream,
                           Xbf + (size_t)m0base * DM, DM, Wqkv_t, DM, DM,
                           qkvbuf, 3072, m0base, bq, bk, bv,
                           (const float*)nullptr, (const __hip_bfloat16*)nullptr,
                           (const float*)nullptr, (const float*)nullptr);
        // attention (ctx written in place into q-cols of qkvbuf)
        hipLaunchKernelGGL(attn_kernel, dim3(rows / 12), dim3(256), 0, stream, qkvbuf);
        // out-proj + bo + residual(x) + LN1 -> y1
        hipLaunchKernelGGL(HIP_KERNEL_NAME(gemm_kernel<1>), dim3(rows / 128, 1), dim3(256), 0, stream,
                           qkvbuf, 3072, Wo_t, 1024, 1024,
                           y1buf, DM, m0base, bo, (const float*)nullptr, (const float*)nullptr,
                           x, (const __hip_bfloat16*)nullptr, ln1g, ln1b);
        // FFN1 + b1 + relu -> h1
        hipLaunchKernelGGL(HIP_KERNEL_NAME(gemm_kernel<2>), dim3(rows / 128, 4), dim3(256), 0, stream,
                           y1buf, DM, W1_t, DM, DM,
                           h1buf, DFF, m0base, b1, (const float*)nullptr, (const float*)nullptr,
                           (const float*)nullptr, (const __hip_bfloat16*)nullptr,
                           (const float*)nullptr, (const float*)nullptr);
        // FFN2 + b2 + residual(y1) + LN2 -> z (scattered (b,t,n,d))
        hipLaunchKernelGGL(HIP_KERNEL_NAME(gemm_kernel<3>), dim3(rows / 128, 1), dim3(256), 0, stream,
                           h1buf, DFF, W2_t, DFF, DFF,
                           z, 0, m0base, b2, (const float*)nullptr, (const float*)nullptr,
                           (const float*)nullptr, y1buf, ln2g, ln2b);
    }

    hipLaunchKernelGGL(mgcn_kernel, dim3(Bsz * SEQ_T, (N_SENSORS + 31) / 32), dim3(256), 0, stream,
                       z, offs, ccols, cvals,
                       offs + (N_SENSORS + 1), ccols + nnz, cvals + nnz,
                       gc, gcb, (float*)d_out);
}

// Round 4
// 1508.620 us; speedup vs baseline: 3.0632x; 1.1910x over previous
//
#include <hip/hip_runtime.h>
#include <hip/hip_bf16.h>

#define N_SENSORS 325
#define SEQ_T 12
#define DM 128
#define NHEADS 8
#define DFF 512

typedef __attribute__((ext_vector_type(8))) short bf16x8;
typedef __attribute__((ext_vector_type(4))) float f32x4;

__device__ __forceinline__ float bfbits2f(short s) {
    return __uint_as_float(((unsigned)(unsigned short)s) << 16);
}
__device__ __forceinline__ short f2bfbits(float f) {
    __hip_bfloat16 h = __float2bfloat16(f);
    return *(short*)&h;
}
__device__ __forceinline__ void gload_lds16(const void* g, void* l) {
    __builtin_amdgcn_global_load_lds((const __attribute__((address_space(1))) void*)g,
                                     (__attribute__((address_space(3))) void*)l, 16, 0, 0);
}

// ---------------------------------------------------------------------------
// CSR build for both sparse supports (blockIdx.x selects support).
// ---------------------------------------------------------------------------
__global__ __launch_bounds__(256) void build_csr_kernel(
    const float* __restrict__ vals0_in, const int* __restrict__ rows0,
    const int* __restrict__ cols0_in,
    const float* __restrict__ vals1_in, const int* __restrict__ rows1,
    const int* __restrict__ cols1_in, int nnz,
    int* __restrict__ offs, int* __restrict__ out_cols,
    float* __restrict__ out_vals)
{
    const int s = blockIdx.x;
    const float* vals = s ? vals1_in : vals0_in;
    const int*   rows = s ? rows1 : rows0;
    const int*   cols = s ? cols1_in : cols0_in;
    offs     += s * (N_SENSORS + 1);
    out_cols += s * nnz;
    out_vals += s * nnz;

    __shared__ int cnt[N_SENSORS];
    __shared__ int cur[N_SENSORS];
    const int tid = threadIdx.x;
    for (int i = tid; i < N_SENSORS; i += 256) cnt[i] = 0;
    __syncthreads();
    for (int e = tid; e < nnz; e += 256) atomicAdd(&cnt[rows[e]], 1);
    __syncthreads();
    if (tid == 0) {
        int acc = 0;
        for (int i = 0; i < N_SENSORS; ++i) { offs[i] = acc; cur[i] = acc; acc += cnt[i]; }
        offs[N_SENSORS] = acc;
    }
    __syncthreads();
    for (int e = tid; e < nnz; e += 256) {
        int r = rows[e];
        int p = atomicAdd(&cur[r], 1);
        out_cols[p] = cols[e];
        out_vals[p] = vals[e];
    }
}

// ---------------------------------------------------------------------------
// prep_misc: W1_t[f][d], W2_t[d][f], Gcat_t[n=mtx*128+dd][k=d],
//            biasYU (u-vector for Y cols, zeros for U cols), b_eff.
// ---------------------------------------------------------------------------
__global__ __launch_bounds__(256) void prep_misc_kernel(
    const float* __restrict__ W1, const float* __restrict__ W2,
    const float* __restrict__ gc, const float* __restrict__ Wk,
    const float* __restrict__ bq, const float* __restrict__ bo,
    const float* __restrict__ bv, const float* __restrict__ Wo,
    __hip_bfloat16* __restrict__ W1_t, __hip_bfloat16* __restrict__ W2_t,
    __hip_bfloat16* __restrict__ Gcat_t,
    float* __restrict__ biasYU, float* __restrict__ beff)
{
    int id = blockIdx.x * 256 + threadIdx.x;   // 182400 items
    if (id < 65536) {
        int f = id >> 7, d = id & 127;
        W1_t[id] = __float2bfloat16(W1[d * 512 + f]);
    } else if (id < 131072) {
        int t = id - 65536;
        int d = t >> 9, f = t & 511;
        W2_t[t] = __float2bfloat16(W2[f * 128 + d]);
    } else if (id < 180224) {
        int t = id - 131072;
        int n = t >> 7, k = t & 127;
        int mtx = n >> 7, dd = n & 127;
        Gcat_t[t] = __float2bfloat16(gc[(k * 3 + mtx) * 128 + dd]);
    } else if (id < 181248) {
        int t = id - 180224;                    // Y-bias u: h*128+dd
        int h = t >> 7, dd = t & 127;
        float a = 0.f;
        for (int c = 0; c < 128; ++c) a += Wk[dd * 1024 + h * 128 + c] * bq[h * 128 + c];
        biasYU[t] = a * 0.08838834764831845f;
    } else if (id < 182272) {
        biasYU[1024 + (id - 181248)] = 0.f;
    } else if (id < 182400) {
        int d = id - 182272;
        float a = bo[d];
        for (int h = 0; h < 8; ++h)
            for (int c = 0; c < 128; ++c)
                a += bv[h * 128 + c] * Wo[h * 16384 + c * 128 + d];
        beff[d] = a;
    }
}

// ---------------------------------------------------------------------------
// fold: Bfold[n][k] (2048x128 bf16):
//   n<1024  (Y): M^T -> (1/sqrt128) * sum_c Wq[k,h,c]*Wk[dd,h,c]
//   n>=1024 (U): P^T -> sum_c Wv[k,h,c]*Wo[h,c,dd]
// ---------------------------------------------------------------------------
__global__ __launch_bounds__(256) void fold_kernel(
    const float* __restrict__ Wq, const float* __restrict__ Wk,
    const float* __restrict__ Wv, const float* __restrict__ Wo,
    __hip_bfloat16* __restrict__ Bfold)
{
    int id = blockIdx.x * 256 + threadIdx.x;   // 262144
    int n = id >> 7, k = id & 127;
    float a = 0.f;
    if (n < 1024) {
        int h = n >> 7, dd = n & 127;
        const float* wq = Wq + k * 1024 + h * 128;
        const float* wk = Wk + dd * 1024 + h * 128;
        for (int c = 0; c < 128; ++c) a += wq[c] * wk[c];
        a *= 0.08838834764831845f;
    } else {
        int h = (n >> 7) & 7, dd = n & 127;
        const float* wv = Wv + k * 1024 + h * 128;
        const float* wo = Wo + h * 16384 + dd;
        for (int c = 0; c < 128; ++c) a += wv[c] * wo[c * 128];
    }
    Bfold[id] = __float2bfloat16(a);
}

// ---------------------------------------------------------------------------
// Fused attention block: 96 rows (8 sensors) per block.
// Per head h: MFMA Yh = X@Bfold[h] (+u bias), Uh = X@Bfold[1024+h];
// VALU: S = Yh@X^T per bn, softmax, out += P@Uh. Then +x +beff, LN1 -> y1.
// X staged in LDS bf16, XOR-swizzled (slot ^= row&7).
// ---------------------------------------------------------------------------
__global__ __launch_bounds__(256) void attn_fused_kernel(
    const float* __restrict__ x,
    const __hip_bfloat16* __restrict__ Bfold,
    const float* __restrict__ biasYU,
    const float* __restrict__ beff,
    const float* __restrict__ ln1g, const float* __restrict__ ln1b,
    __hip_bfloat16* __restrict__ y1)
{
    __shared__ short s_x[96 * 128];
    __shared__ short s_yh[96 * 128];
    __shared__ short s_uh[96 * 128];
    __shared__ float s_P[8][SEQ_T][SEQ_T];
    __shared__ float s_part[96][2][2];

    const int tid = threadIdx.x;
    const int w = tid >> 6, lane = tid & 63;
    const int l15 = lane & 15, g4 = lane >> 4;
    const size_t m0 = (size_t)blockIdx.x * 96;

    // stage x -> swizzled bf16
    for (int i = tid; i < 96 * 128; i += 256) {
        int row = i >> 7, d = i & 127;
        float v = x[m0 * 128 + i];
        int byo = row * 256 + (((d >> 3) ^ (row & 7)) << 4) + (d & 7) * 2;
        *(short*)((char*)s_x + byo) = f2bfbits(v);
    }
    float rout[48];
#pragma unroll
    for (int i = 0; i < 48; ++i) rout[i] = 0.f;
    __syncthreads();

    for (int h = 0; h < NHEADS; ++h) {
        // --- two MFMA GEMMs: Yh (sel=0, +u bias) and Uh (sel=1) ---
#pragma unroll
        for (int sel = 0; sel < 2; ++sel) {
            f32x4 acc[6][2];
#pragma unroll
            for (int fm = 0; fm < 6; ++fm)
#pragma unroll
                for (int fn = 0; fn < 2; ++fn) {
                    float b = (sel == 0) ? biasYU[h * 128 + w * 32 + fn * 16 + l15] : 0.f;
                    acc[fm][fn] = (f32x4){b, b, b, b};
                }
            const __hip_bfloat16* Bp = Bfold + ((size_t)(sel * 1024 + h * 128 + w * 32)) * 128;
#pragma unroll
            for (int ks = 0; ks < 4; ++ks) {
                bf16x8 af[6], bfr[2];
#pragma unroll
                for (int fm = 0; fm < 6; ++fm) {
                    int row = fm * 16 + l15;
                    af[fm] = *(const bf16x8*)((const char*)s_x +
                              row * 256 + ((((ks * 4 + g4) ^ (row & 7))) << 4));
                }
#pragma unroll
                for (int fn = 0; fn < 2; ++fn)
                    bfr[fn] = *(const bf16x8*)((const char*)Bp +
                              ((size_t)(fn * 16 + l15) * 128 + ks * 32 + g4 * 8) * 2);
#pragma unroll
                for (int fm = 0; fm < 6; ++fm)
#pragma unroll
                    for (int fn = 0; fn < 2; ++fn)
                        acc[fm][fn] = __builtin_amdgcn_mfma_f32_16x16x32_bf16(
                            af[fm], bfr[fn], acc[fm][fn], 0, 0, 0);
            }
            short* dstl = sel ? s_uh : s_yh;
#pragma unroll
            for (int fm = 0; fm < 6; ++fm)
#pragma unroll
                for (int fn = 0; fn < 2; ++fn)
#pragma unroll
                    for (int reg = 0; reg < 4; ++reg) {
                        int row = fm * 16 + g4 * 4 + reg;
                        int col = w * 32 + fn * 16 + l15;
                        dstl[row * 128 + col] = f2bfbits(acc[fm][fn][reg]);
                    }
        }
        __syncthreads();

        // --- scores S[bnl][t][s] = Yh[t] . x[s] ---
        for (int it = tid; it < 8 * 144; it += 256) {
            int bnl = it / 144, r = it - bnl * 144;
            int t = r / 12, s2 = r - t * 12;
            int trow = bnl * 12 + t, srow = bnl * 12 + s2;
            float acc = 0.f;
#pragma unroll
            for (int sl = 0; sl < 8; ++sl) {
                bf16x8 yv = *(const bf16x8*)((const char*)s_yh + trow * 256 + sl * 16);
                bf16x8 xv = *(const bf16x8*)((const char*)s_x + srow * 256 + (((sl ^ (srow & 7))) << 4));
#pragma unroll
                for (int j = 0; j < 8; ++j) acc += bfbits2f(yv[j]) * bfbits2f(xv[j]);
            }
            s_P[bnl][t][s2] = acc;
        }
        __syncthreads();

        // --- softmax over s ---
        if (tid < 96) {
            int bnl = tid / 12, t = tid - bnl * 12;
            float m = -1e30f;
#pragma unroll
            for (int s2 = 0; s2 < 12; ++s2) m = fmaxf(m, s_P[bnl][t][s2]);
            float e[12], sum = 0.f;
#pragma unroll
            for (int s2 = 0; s2 < 12; ++s2) { e[s2] = __expf(s_P[bnl][t][s2] - m); sum += e[s2]; }
            float inv = 1.f / sum;
#pragma unroll
            for (int s2 = 0; s2 < 12; ++s2) s_P[bnl][t][s2] = e[s2] * inv;
        }
        __syncthreads();

        // --- out += P @ Uh ---
#pragma unroll
        for (int idx = 0; idx < 48; ++idx) {
            int it = idx * 256 + tid;
            int row = it >> 7, d = it & 127;
            int bnl = row / 12, t = row - bnl * 12;
            float acc = rout[idx];
#pragma unroll
            for (int s2 = 0; s2 < 12; ++s2)
                acc += s_P[bnl][t][s2] * bfbits2f(s_uh[(bnl * 12 + s2) * 128 + d]);
            rout[idx] = acc;
        }
        __syncthreads();   // before next head overwrites s_yh/s_uh/s_P
    }

    // --- residual + beff, LN1, write y1 ---
#pragma unroll
    for (int idx = 0; idx < 48; ++idx) {
        int it = idx * 256 + tid;
        int row = it >> 7, d = it & 127;
        int byo = row * 256 + (((d >> 3) ^ (row & 7)) << 4) + (d & 7) * 2;
        float v = rout[idx] + beff[d] + bfbits2f(*(const short*)((const char*)s_x + byo));
        rout[idx] = v;
        float s = v, ss = v * v;
#pragma unroll
        for (int o = 32; o > 0; o >>= 1) { s += __shfl_down(s, o); ss += __shfl_down(ss, o); }
        if (lane == 0) { s_part[row][w & 1][0] = s; s_part[row][w & 1][1] = ss; }
    }
    __syncthreads();
#pragma unroll
    for (int idx = 0; idx < 48; ++idx) {
        int it = idx * 256 + tid;
        int row = it >> 7, d = it & 127;
        float sum = s_part[row][0][0] + s_part[row][1][0];
        float ssm = s_part[row][0][1] + s_part[row][1][1];
        float mu = sum * (1.f / 128.f);
        float rs = rsqrtf(ssm * (1.f / 128.f) - mu * mu + 1e-3f);
        float yv = (rout[idx] - mu) * rs * ln1g[d] + ln1b[d];
        ((short*)y1)[(m0 + row) * 128 + d] = f2bfbits(yv);
    }
}

// ---------------------------------------------------------------------------
// MFMA GEMM, 128x128 tile, proven staging (round 3). EPI:
//   2 = FFN1: +b1, relu -> bf16 C (stride 512)
//   3 = FFN2: +b2 +resid(y1 bf16) + LN2 -> z bf16 (m-order)
//   4 = P GEMM: n0==0 -> f32 d_out (+gcb); n0>0 -> P12 bf16 [m][256], guarded
// ---------------------------------------------------------------------------
template <int EPI>
__global__ __launch_bounds__(256) void gemm_kernel(
    const __hip_bfloat16* __restrict__ A, int Astride,
    const __hip_bfloat16* __restrict__ Bw, int Bstride, int Ktot,
    __hip_bfloat16* __restrict__ C, int Cstride,
    float* __restrict__ outF, int Mloc,
    const float* __restrict__ bias,
    const __hip_bfloat16* __restrict__ resid,
    const float* __restrict__ lng, const float* __restrict__ lnb)
{
    __shared__ __hip_bfloat16 Alds[128 * 128];
    __shared__ __hip_bfloat16 Blds[128 * 128];
    const int tid = threadIdx.x;
    const int w = tid >> 6, lane = tid & 63;
    const int l15 = lane & 15, g4 = lane >> 4;
    const int m0 = blockIdx.x * 128;
    const int n0 = blockIdx.y * 128;

    f32x4 acc[2][8];
#pragma unroll
    for (int a = 0; a < 2; ++a)
#pragma unroll
        for (int b = 0; b < 8; ++b) acc[a][b] = (f32x4){0.f, 0.f, 0.f, 0.f};

    const int nchunks = Ktot >> 7;
    for (int kc = 0; kc < nchunks; ++kc) {
#pragma unroll
        for (int i = 0; i < 8; ++i) {
            int fs = (w * 8 + i) * 64 + lane;
            int row = fs >> 4, slot = fs & 15;
            int sw = (slot ^ (row & 7)) << 4;
            int rowA = m0 + row;
            if (EPI == 4) rowA = min(rowA, Mloc - 1);
            gload_lds16((const char*)A + ((size_t)rowA * Astride + (size_t)kc * 128) * 2 + sw,
                        (char*)Alds + (size_t)(w * 8 + i) * 1024);
            gload_lds16((const char*)Bw + ((size_t)(n0 + row) * Bstride + (size_t)kc * 128) * 2 + sw,
                        (char*)Blds + (size_t)(w * 8 + i) * 1024);
        }
        __syncthreads();
        const char* Ab = (const char*)Alds;
        const char* Bb = (const char*)Blds;
#pragma unroll
        for (int ks = 0; ks < 4; ++ks) {
            bf16x8 af[2], bfr[8];
#pragma unroll
            for (int fm = 0; fm < 2; ++fm) {
                int row = w * 32 + fm * 16 + l15;
                int c = (ks * 4 + g4) ^ (row & 7);
                af[fm] = *(const bf16x8*)(Ab + row * 256 + c * 16);
            }
#pragma unroll
            for (int fn = 0; fn < 8; ++fn) {
                int row = fn * 16 + l15;
                int c = (ks * 4 + g4) ^ (row & 7);
                bfr[fn] = *(const bf16x8*)(Bb + row * 256 + c * 16);
            }
#pragma unroll
            for (int fm = 0; fm < 2; ++fm)
#pragma unroll
                for (int fn = 0; fn < 8; ++fn)
                    acc[fm][fn] = __builtin_amdgcn_mfma_f32_16x16x32_bf16(
                        af[fm], bfr[fn], acc[fm][fn], 0, 0, 0);
        }
        __syncthreads();
    }

    __hip_bfloat16* Clds = Alds;
    if (EPI == 2) {
#pragma unroll
        for (int fm = 0; fm < 2; ++fm)
#pragma unroll
            for (int reg = 0; reg < 4; ++reg) {
                int mlt = w * 32 + fm * 16 + g4 * 4 + reg;
#pragma unroll
                for (int fn = 0; fn < 8; ++fn) {
                    int nl = fn * 16 + l15;
                    float v = acc[fm][fn][reg] + bias[n0 + nl];
                    Clds[mlt * 128 + nl] = __float2bfloat16(fmaxf(v, 0.f));
                }
            }
    } else if (EPI == 3) {
#pragma unroll
        for (int fm = 0; fm < 2; ++fm)
#pragma unroll
            for (int reg = 0; reg < 4; ++reg) {
                int mlt = w * 32 + fm * 16 + g4 * 4 + reg;
                float v[8], s1 = 0.f, s2 = 0.f;
#pragma unroll
                for (int fn = 0; fn < 8; ++fn) {
                    int nl = fn * 16 + l15;
                    float t = acc[fm][fn][reg] + bias[nl]
                            + bfbits2f(((const short*)resid)[(size_t)(m0 + mlt) * 128 + nl]);
                    v[fn] = t; s1 += t; s2 += t * t;
                }
#pragma unroll
                for (int o = 1; o < 16; o <<= 1) { s1 += __shfl_xor(s1, o); s2 += __shfl_xor(s2, o); }
                float mu = s1 * (1.f / 128.f);
                float rstd = rsqrtf(s2 * (1.f / 128.f) - mu * mu + 1e-3f);
#pragma unroll
                for (int fn = 0; fn < 8; ++fn) {
                    int nl = fn * 16 + l15;
                    float o2 = (v[fn] - mu) * rstd * lng[nl] + lnb[nl];
                    Clds[mlt * 128 + nl] = __float2bfloat16(o2);
                }
            }
    } else { // EPI == 4
        if (n0 == 0) {
#pragma unroll
            for (int fm = 0; fm < 2; ++fm)
#pragma unroll
                for (int reg = 0; reg < 4; ++reg) {
                    int mlt = w * 32 + fm * 16 + g4 * 4 + reg;
                    if (m0 + mlt < Mloc) {
#pragma unroll
                        for (int fn = 0; fn < 8; ++fn) {
                            int nl = fn * 16 + l15;
                            outF[(size_t)(m0 + mlt) * 128 + nl] = acc[fm][fn][reg] + bias[nl];
                        }
                    }
                }
            return;  // uniform per block (n0 is block-uniform)
        }
#pragma unroll
        for (int fm = 0; fm < 2; ++fm)
#pragma unroll
            for (int reg = 0; reg < 4; ++reg) {
                int mlt = w * 32 + fm * 16 + g4 * 4 + reg;
#pragma unroll
                for (int fn = 0; fn < 8; ++fn) {
                    int nl = fn * 16 + l15;
                    Clds[mlt * 128 + nl] = __float2bfloat16(acc[fm][fn][reg]);
                }
            }
    }
    __syncthreads();
#pragma unroll
    for (int i = 0; i < 8; ++i) {
        int fs = i * 256 + tid;
        int row = fs >> 4, slot = fs & 15;
        float4 val = *(const float4*)((const char*)Clds + (size_t)fs * 16);
        if (EPI == 4) {
            if (m0 + row < Mloc)
                *(float4*)((char*)C + ((size_t)(m0 + row) * 256 + (size_t)(n0 - 128) + (size_t)slot * 8) * 2) = val;
        } else {
            *(float4*)((char*)C + ((size_t)(m0 + row) * Cstride + n0) * 2 + (size_t)slot * 16) = val;
        }
    }
}

// ---------------------------------------------------------------------------
// combine: out[m(b,n,t)] += sum_e vals0*P1[m(b,c,t)] + sum_e vals1*P2[...]
// (P0 + gcb already in d_out from gemm<4> n0==0.)
// ---------------------------------------------------------------------------
__global__ __launch_bounds__(256) void combine_kernel(
    float* __restrict__ out, const __hip_bfloat16* __restrict__ P12,
    const int* __restrict__ offs0, const int* __restrict__ cols0,
    const float* __restrict__ vals0,
    const int* __restrict__ offs1, const int* __restrict__ cols1,
    const float* __restrict__ vals1,
    int b0, int mbase)
{
    const int btl = blockIdx.x;
    const int b = b0 + btl / 12, t = btl - (btl / 12) * 12;
    const int n0 = blockIdx.y * 32;
    const int tid = threadIdx.x;
    const int d = tid & 127, g = tid >> 7;
    const short* P = (const short*)P12;
    for (int rr = g; rr < 32; rr += 2) {
        int n = n0 + rr;
        if (n >= N_SENSORS) break;
        size_t orow = ((size_t)(b * N_SENSORS + n) * 12 + t) * 128;
        float acc = out[orow + d];
        int e0 = offs0[n], e1 = offs0[n + 1];
        for (int e = e0; e < e1; ++e) {
            int mloc = (b * N_SENSORS + cols0[e]) * 12 + t - mbase;
            acc += vals0[e] * bfbits2f(P[(size_t)mloc * 256 + d]);
        }
        e0 = offs1[n]; e1 = offs1[n + 1];
        for (int e = e0; e < e1; ++e) {
            int mloc = (b * N_SENSORS + cols1[e]) * 12 + t - mbase;
            acc += vals1[e] * bfbits2f(P[(size_t)mloc * 256 + 128 + d]);
        }
        out[orow + d] = acc;
    }
}

// ---------------------------------------------------------------------------
extern "C" void kernel_launch(void* const* d_in, const int* in_sizes, int n_in,
                              void* d_out, int out_size, void* d_ws, size_t ws_size,
                              hipStream_t stream)
{
    const float* x    = (const float*)d_in[0];
    const float* Wq   = (const float*)d_in[1];
    const float* bq   = (const float*)d_in[2];
    const float* Wk   = (const float*)d_in[3];
    const float* bk   = (const float*)d_in[4];  (void)bk; // softmax-invariant
    const float* Wv   = (const float*)d_in[5];
    const float* bv   = (const float*)d_in[6];
    const float* Wo   = (const float*)d_in[7];
    const float* bo   = (const float*)d_in[8];
    const float* ln1g = (const float*)d_in[9];
    const float* ln1b = (const float*)d_in[10];
    const float* W1   = (const float*)d_in[11];
    const float* b1   = (const float*)d_in[12];
    const float* W2   = (const float*)d_in[13];
    const float* b2   = (const float*)d_in[14];
    const float* ln2g = (const float*)d_in[15];
    const float* ln2b = (const float*)d_in[16];
    const float* gc   = (const float*)d_in[17];
    const float* gcb  = (const float*)d_in[18];
    const float* s0v  = (const float*)d_in[19];
    const float* s1v  = (const float*)d_in[20];
    const int*   s0r  = (const int*)d_in[21];
    const int*   s0c  = (const int*)d_in[22];
    const int*   s1r  = (const int*)d_in[23];
    const int*   s1c  = (const int*)d_in[24];
    const int nnz  = in_sizes[19];
    const int BN   = in_sizes[0] / (SEQ_T * DM);   // 10400
    const int Bsz  = BN / N_SENSORS;               // 32
    const int Mtot = BN * SEQ_T;                   // 124800

    char* ws = (char*)d_ws;
    size_t off = 0;
    auto alloc = [&](size_t bytes) {
        char* r = ws + off;
        off = (off + bytes + 255) & ~(size_t)255;
        return r;
    };

    int*   offs   = (int*)alloc((size_t)2 * (N_SENSORS + 1) * 4);
    int*   ccols  = (int*)alloc((size_t)2 * nnz * 4);
    float* cvals  = (float*)alloc((size_t)2 * nnz * 4);
    __hip_bfloat16* Bfold  = (__hip_bfloat16*)alloc((size_t)2048 * 128 * 2);
    float* biasYU = (float*)alloc(2048 * 4);
    float* beff   = (float*)alloc(128 * 4);
    __hip_bfloat16* W1_t   = (__hip_bfloat16*)alloc((size_t)65536 * 2);
    __hip_bfloat16* W2_t   = (__hip_bfloat16*)alloc((size_t)65536 * 2);
    __hip_bfloat16* Gcat_t = (__hip_bfloat16*)alloc((size_t)49152 * 2);

    const int hrows  = (Mtot / 2);                    // 62400 (Bsz even)
    const int htiles = (hrows + 127) / 128;           // 488
    size_t y1_bytes   = (size_t)Mtot * 128 * 2;       // 31.95 MB
    size_t p12_bytes  = (size_t)htiles * 128 * 256 * 2; // 31.98 MB
    __hip_bfloat16* y1 = (__hip_bfloat16*)alloc(y1_bytes > p12_bytes ? y1_bytes : p12_bytes);
    __hip_bfloat16* z  = (__hip_bfloat16*)alloc((size_t)Mtot * 128 * 2);
    const int QR = 24960;                              // FFN stripe rows (5 x)
    __hip_bfloat16* h1 = (__hip_bfloat16*)alloc((size_t)QR * 512 * 2);
    __hip_bfloat16* P12 = y1;                          // reuse after FFN

    hipLaunchKernelGGL(build_csr_kernel, dim3(2), dim3(256), 0, stream,
                       s0v, s0r, s0c, s1v, s1r, s1c, nnz, offs, ccols, cvals);
    hipLaunchKernelGGL(prep_misc_kernel, dim3(713), dim3(256), 0, stream,
                       W1, W2, gc, Wk, bq, bo, bv, Wo, W1_t, W2_t, Gcat_t, biasYU, beff);
    hipLaunchKernelGGL(fold_kernel, dim3(1024), dim3(256), 0, stream,
                       Wq, Wk, Wv, Wo, Bfold);

    hipLaunchKernelGGL(attn_fused_kernel, dim3(Mtot / 96), dim3(256), 0, stream,
                       x, Bfold, biasYU, beff, ln1g, ln1b, y1);

    for (int q0 = 0; q0 < Mtot; q0 += QR) {
        int rows = (QR < Mtot - q0) ? QR : (Mtot - q0);
        hipLaunchKernelGGL(HIP_KERNEL_NAME(gemm_kernel<2>), dim3(rows / 128, 4), dim3(256), 0, stream,
                           y1 + (size_t)q0 * 128, 128, W1_t, 128, 128,
                           h1, 512, (float*)nullptr, 1 << 30,
                           b1, (const __hip_bfloat16*)nullptr,
                           (const float*)nullptr, (const float*)nullptr);
        hipLaunchKernelGGL(HIP_KERNEL_NAME(gemm_kernel<3>), dim3(rows / 128, 1), dim3(256), 0, stream,
                           h1, 512, W2_t, 512, 512,
                           z + (size_t)q0 * 128, 128, (float*)nullptr, 1 << 30,
                           b2, y1 + (size_t)q0 * 128, ln2g, ln2b);
    }

    for (int half = 0; half < 2; ++half) {
        size_t mb = (size_t)half * hrows;
        int Mloc = (half == 0) ? htiles * 128 : (Mtot - (int)mb);
        hipLaunchKernelGGL(HIP_KERNEL_NAME(gemm_kernel<4>), dim3(htiles, 3), dim3(256), 0, stream,
                           z + mb * 128, 128, Gcat_t, 128, 128,
                           P12, 256, (float*)d_out + mb * 128, Mloc,
                           gcb, (const __hip_bfloat16*)nullptr,
                           (const float*)nullptr, (const float*)nullptr);
        hipLaunchKernelGGL(combine_kernel, dim3((Bsz / 2) * SEQ_T, (N_SENSORS + 31) / 32), dim3(256), 0, stream,
                           (float*)d_out, P12,
                           offs, ccols, cvals,
                           offs + (N_SENSORS + 1), ccols + nnz, cvals + nnz,
                           half * (Bsz / 2), (int)mb);
    }
}

// Round 6
// 1073.263 us; speedup vs baseline: 4.3057x; 1.4056x over previous
//
#include <hip/hip_runtime.h>
#include <hip/hip_bf16.h>

#define N_SENSORS 325
#define SEQ_T 12
#define DM 128
#define NHEADS 8
#define DFF 512

typedef __attribute__((ext_vector_type(8))) short bf16x8;
typedef __attribute__((ext_vector_type(4))) float f32x4;

__device__ __forceinline__ float bfbits2f(short s) {
    return __uint_as_float(((unsigned)(unsigned short)s) << 16);
}
__device__ __forceinline__ short f2bfbits(float f) {
    __hip_bfloat16 h = __float2bfloat16(f);
    return *(short*)&h;
}
__device__ __forceinline__ unsigned pk2(float a, float b) {
    return (unsigned)(unsigned short)f2bfbits(a) |
           ((unsigned)(unsigned short)f2bfbits(b) << 16);
}
__device__ __forceinline__ void gload_lds16(const void* g, void* l) {
    __builtin_amdgcn_global_load_lds((const __attribute__((address_space(1))) void*)g,
                                     (__attribute__((address_space(3))) void*)l, 16, 0, 0);
}

// ---------------------------------------------------------------------------
// CSR build for both sparse supports.
// ---------------------------------------------------------------------------
__global__ __launch_bounds__(256) void build_csr_kernel(
    const float* __restrict__ vals0_in, const int* __restrict__ rows0,
    const int* __restrict__ cols0_in,
    const float* __restrict__ vals1_in, const int* __restrict__ rows1,
    const int* __restrict__ cols1_in, int nnz,
    int* __restrict__ offs, int* __restrict__ out_cols,
    float* __restrict__ out_vals)
{
    const int s = blockIdx.x;
    const float* vals = s ? vals1_in : vals0_in;
    const int*   rows = s ? rows1 : rows0;
    const int*   cols = s ? cols1_in : cols0_in;
    offs     += s * (N_SENSORS + 1);
    out_cols += s * nnz;
    out_vals += s * nnz;

    __shared__ int cnt[N_SENSORS];
    __shared__ int cur[N_SENSORS];
    const int tid = threadIdx.x;
    for (int i = tid; i < N_SENSORS; i += 256) cnt[i] = 0;
    __syncthreads();
    for (int e = tid; e < nnz; e += 256) atomicAdd(&cnt[rows[e]], 1);
    __syncthreads();
    if (tid == 0) {
        int acc = 0;
        for (int i = 0; i < N_SENSORS; ++i) { offs[i] = acc; cur[i] = acc; acc += cnt[i]; }
        offs[N_SENSORS] = acc;
    }
    __syncthreads();
    for (int e = tid; e < nnz; e += 256) {
        int r = rows[e];
        int p = atomicAdd(&cur[r], 1);
        out_cols[p] = cols[e];
        out_vals[p] = vals[e];
    }
}

// ---------------------------------------------------------------------------
// prep: W1_t[f][d], W2_t[d][f], Gcat_t[dd][mtx*128+k], biasU (u), beff.
// ---------------------------------------------------------------------------
__global__ __launch_bounds__(256) void prep_misc_kernel(
    const float* __restrict__ W1, const float* __restrict__ W2,
    const float* __restrict__ gc, const float* __restrict__ Wk,
    const float* __restrict__ bq, const float* __restrict__ bo,
    const float* __restrict__ bv, const float* __restrict__ Wo,
    __hip_bfloat16* __restrict__ W1_t, __hip_bfloat16* __restrict__ W2_t,
    __hip_bfloat16* __restrict__ Gcat_t,
    float* __restrict__ biasU, float* __restrict__ beff)
{
    int id = blockIdx.x * 256 + threadIdx.x;   // 181376 items
    if (id < 65536) {
        int f = id >> 7, d = id & 127;
        W1_t[id] = __float2bfloat16(W1[d * 512 + f]);
    } else if (id < 131072) {
        int t = id - 65536;
        int d = t >> 9, f = t & 511;
        W2_t[t] = __float2bfloat16(W2[f * 128 + d]);
    } else if (id < 180224) {
        int t = id - 131072;
        int dd = t / 384, rem = t - dd * 384;
        int mtx = rem >> 7, kd = rem & 127;
        Gcat_t[t] = __float2bfloat16(gc[(kd * 3 + mtx) * 128 + dd]);
    } else if (id < 181248) {
        int t = id - 180224;                    // u: h*128+dd
        int h = t >> 7, dd = t & 127;
        float a = 0.f;
        for (int c = 0; c < 128; ++c) a += Wk[dd * 1024 + h * 128 + c] * bq[h * 128 + c];
        biasU[t] = a * 0.08838834764831845f;
    } else if (id < 181376) {
        int d = id - 181248;
        float a = bo[d];
        for (int h = 0; h < 8; ++h)
            for (int c = 0; c < 128; ++c)
                a += bv[h * 128 + c] * Wo[h * 16384 + c * 128 + d];
        beff[d] = a;
    }
}

// ---------------------------------------------------------------------------
// Bfold[n][k] (2048x128): n<1024: (WqWk^T)^T scaled; n>=1024: (WvWo)^T.
// ---------------------------------------------------------------------------
__global__ __launch_bounds__(256) void fold_kernel(
    const float* __restrict__ Wq, const float* __restrict__ Wk,
    const float* __restrict__ Wv, const float* __restrict__ Wo,
    __hip_bfloat16* __restrict__ Bfold)
{
    int id = blockIdx.x * 256 + threadIdx.x;   // 262144
    int n = id >> 7, k = id & 127;
    float a = 0.f;
    if (n < 1024) {
        int h = n >> 7, dd = n & 127;
        const float* wq = Wq + k * 1024 + h * 128;
        const float* wk = Wk + dd * 1024 + h * 128;
        for (int c = 0; c < 128; ++c) a += wq[c] * wk[c];
        a *= 0.08838834764831845f;
    } else {
        int h = (n >> 7) & 7, dd = n & 127;
        const float* wv = Wv + k * 1024 + h * 128;
        const float* wo = Wo + h * 16384 + dd;
        for (int c = 0; c < 128; ++c) a += wv[c] * wo[c * 128];
    }
    Bfold[id] = __float2bfloat16(a);
}

// ---------------------------------------------------------------------------
// attn v2: 96 rows (8 bn) per block; all dense phases on MFMA.
//  per head: Y = X@M^T + u  (MFMA, -> s_yut swizzled)
//            S tiles (|i-j|<=1) = Y@X^T (MFMA, predicated write to s_s)
//            softmax -> s_p (block-diag bf16 96x104)
//            U = X@P^T (MFMA) -> s_yut as U^T [128][104]
//            accO += P~ @ U^T (MFMA, K=96)
//  epilogue: + beff + x, LN1 -> y1 (bf16, m=(b,n,t) order)
// ---------------------------------------------------------------------------
__global__ __launch_bounds__(256) void attn_fused_kernel(
    const float* __restrict__ x,
    const __hip_bfloat16* __restrict__ Bfold,
    const float* __restrict__ biasU,
    const float* __restrict__ beff,
    const float* __restrict__ ln1g, const float* __restrict__ ln1b,
    __hip_bfloat16* __restrict__ y1)
{
    __shared__ __align__(16) char s_x[24576];    // [96][128] bf16 swizzled
    __shared__ __align__(16) char s_yut[26624];  // Y swz [96][128] / U^T [128][104]
    __shared__ __align__(16) char s_p[19968];    // P~ bf16 [96][104]
    __shared__ float s_s[96][16];
    __shared__ float s_stats[96][4][2];

    const int tid = threadIdx.x;
    const int w = tid >> 6, lane = tid & 63;
    const int l15 = lane & 15, g4 = lane >> 4;
    const size_t m0 = (size_t)blockIdx.x * 96;

    // ---- stage x -> swizzled bf16
    {
        const float4* xg = (const float4*)(x + m0 * 128);
#pragma unroll
        for (int i = 0; i < 12; ++i) {
            int fi = i * 256 + tid;        // float4 idx; 32 per row
            int row = fi >> 5;
            int d0 = (fi & 31) * 4;
            float4 v = xg[fi];
            int base = row * 256 + (((d0 >> 3) ^ (row & 7)) << 4) + (d0 & 7) * 2;
            *(unsigned*)(s_x + base)     = pk2(v.x, v.y);
            *(unsigned*)(s_x + base + 4) = pk2(v.z, v.w);
        }
    }
    // ---- zero P~ once (positions written each head are identical)
    for (int i = tid; i < 1248; i += 256) *(f32x4*)(s_p + i * 16) = (f32x4){0, 0, 0, 0};

    f32x4 accO[6][2];
#pragma unroll
    for (int fm = 0; fm < 6; ++fm)
#pragma unroll
        for (int fn = 0; fn < 2; ++fn) accO[fm][fn] = (f32x4){0, 0, 0, 0};
    __syncthreads();

    for (int h = 0; h < NHEADS; ++h) {
        // ======== Y ========
        {
            f32x4 acc[6][2];
#pragma unroll
            for (int fn = 0; fn < 2; ++fn) {
                float b = biasU[h * 128 + w * 32 + fn * 16 + l15];
#pragma unroll
                for (int fm = 0; fm < 6; ++fm) acc[fm][fn] = (f32x4){b, b, b, b};
            }
            const char* Bp = (const char*)(Bfold + (size_t)(h * 128 + w * 32) * 128);
#pragma unroll
            for (int ks = 0; ks < 4; ++ks) {
                bf16x8 af[6], bfr[2];
#pragma unroll
                for (int fm = 0; fm < 6; ++fm) {
                    int row = fm * 16 + l15;
                    af[fm] = *(const bf16x8*)(s_x + row * 256 + (((ks * 4 + g4) ^ (row & 7)) << 4));
                }
#pragma unroll
                for (int fn = 0; fn < 2; ++fn)
                    bfr[fn] = *(const bf16x8*)(Bp + ((size_t)(fn * 16 + l15) * 128 + (ks * 4 + g4) * 8) * 2);
#pragma unroll
                for (int fm = 0; fm < 6; ++fm)
#pragma unroll
                    for (int fn = 0; fn < 2; ++fn)
                        acc[fm][fn] = __builtin_amdgcn_mfma_f32_16x16x32_bf16(
                            af[fm], bfr[fn], acc[fm][fn], 0, 0, 0);
            }
#pragma unroll
            for (int fm = 0; fm < 6; ++fm)
#pragma unroll
                for (int fn = 0; fn < 2; ++fn)
#pragma unroll
                    for (int reg = 0; reg < 4; ++reg) {
                        int row = fm * 16 + g4 * 4 + reg;
                        int col = w * 32 + fn * 16 + l15;
                        *(short*)(s_yut + row * 256 + (((col >> 3) ^ (row & 7)) << 4) + (col & 7) * 2)
                            = f2bfbits(acc[fm][fn][reg]);
                    }
        }
        __syncthreads();   // bar1

        // ======== S tiles ========
#pragma unroll
        for (int q = 0; q < 4; ++q) {
            int tt = w + q * 4;
            int ti, tj;
            if (tt < 6)       { ti = tt;      tj = tt; }
            else if (tt < 11) { ti = tt - 6;  tj = tt - 5; }
            else              { ti = tt - 10; tj = tt - 11; }
            f32x4 sa = (f32x4){0, 0, 0, 0};
#pragma unroll
            for (int ks = 0; ks < 4; ++ks) {
                int ra = ti * 16 + l15;
                int rb = tj * 16 + l15;
                bf16x8 af = *(const bf16x8*)(s_yut + ra * 256 + (((ks * 4 + g4) ^ (ra & 7)) << 4));
                bf16x8 bf = *(const bf16x8*)(s_x   + rb * 256 + (((ks * 4 + g4) ^ (rb & 7)) << 4));
                sa = __builtin_amdgcn_mfma_f32_16x16x32_bf16(af, bf, sa, 0, 0, 0);
            }
#pragma unroll
            for (int reg = 0; reg < 4; ++reg) {
                int r = ti * 16 + g4 * 4 + reg;
                int c = tj * 16 + l15;
                if (r / 12 == c / 12) s_s[r][c - (c / 12) * 12] = sa[reg];
            }
        }
        __syncthreads();   // bar2

        // ======== softmax -> P~ ========
        if (tid < 96) {
            int row = tid, bnl = row / 12;
            float m = -1e30f;
#pragma unroll
            for (int s2 = 0; s2 < 12; ++s2) m = fmaxf(m, s_s[row][s2]);
            float e[12], sum = 0.f;
#pragma unroll
            for (int s2 = 0; s2 < 12; ++s2) { e[s2] = __expf(s_s[row][s2] - m); sum += e[s2]; }
            float inv = 1.f / sum;
#pragma unroll
            for (int jj = 0; jj < 6; ++jj)
                *(unsigned*)(s_p + row * 208 + bnl * 24 + jj * 4) =
                    pk2(e[2 * jj] * inv, e[2 * jj + 1] * inv);
        }

        // ======== U (writes U^T over s_yut; Y dead) ========
        {
            f32x4 acc[6][2];
#pragma unroll
            for (int fm = 0; fm < 6; ++fm)
#pragma unroll
                for (int fn = 0; fn < 2; ++fn) acc[fm][fn] = (f32x4){0, 0, 0, 0};
            const char* Bp = (const char*)(Bfold + (size_t)(1024 + h * 128 + w * 32) * 128);
#pragma unroll
            for (int ks = 0; ks < 4; ++ks) {
                bf16x8 af[6], bfr[2];
#pragma unroll
                for (int fm = 0; fm < 6; ++fm) {
                    int row = fm * 16 + l15;
                    af[fm] = *(const bf16x8*)(s_x + row * 256 + (((ks * 4 + g4) ^ (row & 7)) << 4));
                }
#pragma unroll
                for (int fn = 0; fn < 2; ++fn)
                    bfr[fn] = *(const bf16x8*)(Bp + ((size_t)(fn * 16 + l15) * 128 + (ks * 4 + g4) * 8) * 2);
#pragma unroll
                for (int fm = 0; fm < 6; ++fm)
#pragma unroll
                    for (int fn = 0; fn < 2; ++fn)
                        acc[fm][fn] = __builtin_amdgcn_mfma_f32_16x16x32_bf16(
                            af[fm], bfr[fn], acc[fm][fn], 0, 0, 0);
            }
            __syncthreads();   // ensure S-phase reads of s_yut done before overwrite
#pragma unroll
            for (int fm = 0; fm < 6; ++fm)
#pragma unroll
                for (int fn = 0; fn < 2; ++fn) {
                    int d = w * 32 + fn * 16 + l15;
                    int s0 = fm * 16 + g4 * 4;
                    *(unsigned*)(s_yut + d * 208 + s0 * 2)     = pk2(acc[fm][fn][0], acc[fm][fn][1]);
                    *(unsigned*)(s_yut + d * 208 + s0 * 2 + 4) = pk2(acc[fm][fn][2], acc[fm][fn][3]);
                }
        }
        __syncthreads();   // bar3

        // ======== accO += P~ @ U^T ========
#pragma unroll
        for (int ks = 0; ks < 3; ++ks) {
            bf16x8 af[6], bfr[2];
#pragma unroll
            for (int fm = 0; fm < 6; ++fm)
                af[fm] = *(const bf16x8*)(s_p + (fm * 16 + l15) * 208 + (ks * 4 + g4) * 16);
#pragma unroll
            for (int fn = 0; fn < 2; ++fn)
                bfr[fn] = *(const bf16x8*)(s_yut + (w * 32 + fn * 16 + l15) * 208 + (ks * 4 + g4) * 16);
#pragma unroll
            for (int fm = 0; fm < 6; ++fm)
#pragma unroll
                for (int fn = 0; fn < 2; ++fn)
                    accO[fm][fn] = __builtin_amdgcn_mfma_f32_16x16x32_bf16(
                        af[fm], bfr[fn], accO[fm][fn], 0, 0, 0);
        }
        __syncthreads();   // bar4 (protect s_yut/s_p for next head)
    }

    // ======== epilogue: +beff +x, LN1 ========
#pragma unroll
    for (int fm = 0; fm < 6; ++fm)
#pragma unroll
        for (int reg = 0; reg < 4; ++reg) {
            int row = fm * 16 + g4 * 4 + reg;
            float s1 = 0.f, s2 = 0.f;
#pragma unroll
            for (int fn = 0; fn < 2; ++fn) {
                int col = w * 32 + fn * 16 + l15;
                float xr = bfbits2f(*(const short*)(s_x + row * 256 +
                             (((col >> 3) ^ (row & 7)) << 4) + (col & 7) * 2));
                float v = accO[fm][fn][reg] + beff[col] + xr;
                accO[fm][fn][reg] = v;
                s1 += v; s2 += v * v;
            }
#pragma unroll
            for (int o = 1; o < 16; o <<= 1) { s1 += __shfl_xor(s1, o); s2 += __shfl_xor(s2, o); }
            if (l15 == 0) { s_stats[row][w][0] = s1; s_stats[row][w][1] = s2; }
        }
    __syncthreads();
#pragma unroll
    for (int fm = 0; fm < 6; ++fm)
#pragma unroll
        for (int reg = 0; reg < 4; ++reg) {
            int row = fm * 16 + g4 * 4 + reg;
            float S1 = s_stats[row][0][0] + s_stats[row][1][0] + s_stats[row][2][0] + s_stats[row][3][0];
            float S2 = s_stats[row][0][1] + s_stats[row][1][1] + s_stats[row][2][1] + s_stats[row][3][1];
            float mu = S1 * (1.f / 128.f);
            float rs = rsqrtf(S2 * (1.f / 128.f) - mu * mu + 1e-3f);
#pragma unroll
            for (int fn = 0; fn < 2; ++fn) {
                int col = w * 32 + fn * 16 + l15;
                float y = (accO[fm][fn][reg] - mu) * rs * ln1g[col] + ln1b[col];
                *(short*)(s_yut + row * 256 + col * 2) = f2bfbits(y);   // linear stage
            }
        }
    __syncthreads();
#pragma unroll
    for (int i = 0; i < 6; ++i) {
        int idx = i * 256 + tid;          // 1536 x 16B
        int row = idx >> 4, slot = idx & 15;
        *(float4*)((char*)y1 + (m0 + row) * 256 + slot * 16) =
            *(const float4*)(s_yut + idx * 16);
    }
}

// ---------------------------------------------------------------------------
// MFMA GEMM, 128x128 tile. EPI:
//   2 = FFN1: +b1, relu -> bf16 C (stride 512)
//   3 = FFN2: +b2 +resid(y1) + LN2 -> z bf16, rows scattered (b,n,t)->(b,t,n)
//   5 = MGCN: A chunks {A,A1,A2}, +gcb -> f32 d_out rows (b,t,n)->(b,n,t)
// ---------------------------------------------------------------------------
template <int EPI>
__global__ __launch_bounds__(256) void gemm_kernel(
    const __hip_bfloat16* __restrict__ A, const __hip_bfloat16* __restrict__ A1,
    const __hip_bfloat16* __restrict__ A2, int Astride,
    const __hip_bfloat16* __restrict__ Bw, int Bstride, int Ktot,
    __hip_bfloat16* __restrict__ C, int Cstride,
    float* __restrict__ outF, int Mloc, int m0base,
    const float* __restrict__ bias,
    const __hip_bfloat16* __restrict__ resid,
    const float* __restrict__ lng, const float* __restrict__ lnb)
{
    __shared__ __align__(16) char s_lds[65536];
    __hip_bfloat16* Alds = (__hip_bfloat16*)s_lds;
    __hip_bfloat16* Blds = (__hip_bfloat16*)(s_lds + 32768);
    const int tid = threadIdx.x;
    const int w = tid >> 6, lane = tid & 63;
    const int l15 = lane & 15, g4 = lane >> 4;
    const int m0 = blockIdx.x * 128;
    const int n0 = blockIdx.y * 128;

    f32x4 acc[2][8];
#pragma unroll
    for (int a = 0; a < 2; ++a)
#pragma unroll
        for (int b = 0; b < 8; ++b) acc[a][b] = (f32x4){0.f, 0.f, 0.f, 0.f};

    const int nchunks = Ktot >> 7;
    for (int kc = 0; kc < nchunks; ++kc) {
        const __hip_bfloat16* Asel = A;
        size_t koff = (size_t)kc * 128;
        if (EPI == 5) { Asel = (kc == 0) ? A : (kc == 1 ? A1 : A2); koff = 0; }
#pragma unroll
        for (int i = 0; i < 8; ++i) {
            int fs = (w * 8 + i) * 64 + lane;
            int row = fs >> 4, slot = fs & 15;
            int sw = (slot ^ (row & 7)) << 4;
            int rowA = m0 + row;
            if (EPI == 5) rowA = min(rowA, Mloc - 1);
            gload_lds16((const char*)Asel + ((size_t)rowA * Astride + koff) * 2 + sw,
                        (char*)Alds + (size_t)(w * 8 + i) * 1024);
            gload_lds16((const char*)Bw + ((size_t)(n0 + row) * Bstride + (size_t)kc * 128) * 2 + sw,
                        (char*)Blds + (size_t)(w * 8 + i) * 1024);
        }
        __syncthreads();
        const char* Ab = (const char*)Alds;
        const char* Bb = (const char*)Blds;
#pragma unroll
        for (int ks = 0; ks < 4; ++ks) {
            bf16x8 af[2], bfr[8];
#pragma unroll
            for (int fm = 0; fm < 2; ++fm) {
                int row = w * 32 + fm * 16 + l15;
                int c = (ks * 4 + g4) ^ (row & 7);
                af[fm] = *(const bf16x8*)(Ab + row * 256 + c * 16);
            }
#pragma unroll
            for (int fn = 0; fn < 8; ++fn) {
                int row = fn * 16 + l15;
                int c = (ks * 4 + g4) ^ (row & 7);
                bfr[fn] = *(const bf16x8*)(Bb + row * 256 + c * 16);
            }
#pragma unroll
            for (int fm = 0; fm < 2; ++fm)
#pragma unroll
                for (int fn = 0; fn < 8; ++fn)
                    acc[fm][fn] = __builtin_amdgcn_mfma_f32_16x16x32_bf16(
                        af[fm], bfr[fn], acc[fm][fn], 0, 0, 0);
        }
        __syncthreads();
    }

    if (EPI == 2) {
        __hip_bfloat16* Clds = Alds;
#pragma unroll
        for (int fm = 0; fm < 2; ++fm)
#pragma unroll
            for (int reg = 0; reg < 4; ++reg) {
                int mlt = w * 32 + fm * 16 + g4 * 4 + reg;
#pragma unroll
                for (int fn = 0; fn < 8; ++fn) {
                    int nl = fn * 16 + l15;
                    float v = acc[fm][fn][reg] + bias[n0 + nl];
                    Clds[mlt * 128 + nl] = __float2bfloat16(fmaxf(v, 0.f));
                }
            }
        __syncthreads();
#pragma unroll
        for (int i = 0; i < 8; ++i) {
            int fs = i * 256 + tid;
            int row = fs >> 4, slot = fs & 15;
            *(float4*)((char*)C + ((size_t)(m0 + row) * Cstride + n0) * 2 + (size_t)slot * 16) =
                *(const float4*)((const char*)Clds + (size_t)fs * 16);
        }
    } else if (EPI == 3) {
        __hip_bfloat16* Clds = Alds;
#pragma unroll
        for (int fm = 0; fm < 2; ++fm)
#pragma unroll
            for (int reg = 0; reg < 4; ++reg) {
                int mlt = w * 32 + fm * 16 + g4 * 4 + reg;
                float v[8], s1 = 0.f, s2 = 0.f;
#pragma unroll
                for (int fn = 0; fn < 8; ++fn) {
                    int nl = fn * 16 + l15;
                    float t = acc[fm][fn][reg] + bias[nl]
                            + bfbits2f(((const short*)resid)[(size_t)(m0 + mlt) * 128 + nl]);
                    v[fn] = t; s1 += t; s2 += t * t;
                }
#pragma unroll
                for (int o = 1; o < 16; o <<= 1) { s1 += __shfl_xor(s1, o); s2 += __shfl_xor(s2, o); }
                float mu = s1 * (1.f / 128.f);
                float rstd = rsqrtf(s2 * (1.f / 128.f) - mu * mu + 1e-3f);
#pragma unroll
                for (int fn = 0; fn < 8; ++fn) {
                    int nl = fn * 16 + l15;
                    Clds[mlt * 128 + nl] = __float2bfloat16((v[fn] - mu) * rstd * lng[nl] + lnb[nl]);
                }
            }
        __syncthreads();
#pragma unroll
        for (int i = 0; i < 8; ++i) {
            int fs = i * 256 + tid;
            int row = fs >> 4, slot = fs & 15;
            int m_g = m0base + m0 + row;
            int bn = m_g / 12, t = m_g - bn * 12;
            int b = bn / N_SENSORS, ns = bn - b * N_SENSORS;
            size_t zrow = (size_t)(b * 12 + t) * N_SENSORS + ns;
            *(float4*)((char*)C + zrow * 256 + (size_t)slot * 16) =
                *(const float4*)((const char*)Alds + (size_t)fs * 16);
        }
    } else {  // EPI == 5
        float* Cf = (float*)s_lds;
#pragma unroll
        for (int fm = 0; fm < 2; ++fm)
#pragma unroll
            for (int reg = 0; reg < 4; ++reg) {
                int mlt = w * 32 + fm * 16 + g4 * 4 + reg;
#pragma unroll
                for (int fn = 0; fn < 8; ++fn) {
                    int nl = fn * 16 + l15;
                    Cf[mlt * 128 + nl] = acc[fm][fn][reg] + bias[nl];
                }
            }
        __syncthreads();
#pragma unroll
        for (int i = 0; i < 16; ++i) {
            int fs = i * 256 + tid;
            int row = fs >> 5, slot = fs & 31;
            if (m0 + row < Mloc) {
                int mg = m0base + m0 + row;        // (b,t,n) order
                int b = mg / 3900, r = mg - b * 3900;
                int t = r / N_SENSORS, n = r - t * N_SENSORS;
                size_t orow = (size_t)(b * N_SENSORS + n) * 12 + t;
                *(float4*)(outF + orow * 128 + slot * 4) =
                    *(const float4*)(s_lds + (size_t)fs * 16);
            }
        }
    }
}

// ---------------------------------------------------------------------------
// combine: x1/x2 = S0/S1 @ z  (per (b,t), gather rows of z's 83 KB window)
// ---------------------------------------------------------------------------
__global__ __launch_bounds__(256) void combine_kernel(
    const __hip_bfloat16* __restrict__ z,
    const int* __restrict__ offs, const int* __restrict__ ccols,
    const float* __restrict__ cvals, int nnz,
    __hip_bfloat16* __restrict__ x1, __hip_bfloat16* __restrict__ x2,
    int bt0)
{
    const int lbt = blockIdx.x;
    const int nc = blockIdx.y;
    const int tid = threadIdx.x;
    const int d = tid & 127, sup = tid >> 7;
    const int* Offs = offs + sup * (N_SENSORS + 1);
    const int* Cols = ccols + sup * nnz;
    const float* Vals = cvals + sup * nnz;
    const short* zb = (const short*)z + (size_t)(bt0 + lbt) * N_SENSORS * 128;
    short* outp = (short*)(sup ? x2 : x1) + (size_t)lbt * N_SENSORS * 128;
    int n1 = min(65 * (nc + 1), N_SENSORS);
    for (int n = nc * 65; n < n1; ++n) {
        float acc = 0.f;
        int e0 = Offs[n], e1 = Offs[n + 1];
        for (int e = e0; e < e1; ++e)
            acc += Vals[e] * bfbits2f(zb[Cols[e] * 128 + d]);
        outp[n * 128 + d] = f2bfbits(acc);
    }
}

// ---------------------------------------------------------------------------
extern "C" void kernel_launch(void* const* d_in, const int* in_sizes, int n_in,
                              void* d_out, int out_size, void* d_ws, size_t ws_size,
                              hipStream_t stream)
{
    const float* x    = (const float*)d_in[0];
    const float* Wq   = (const float*)d_in[1];
    const float* bq   = (const float*)d_in[2];
    const float* Wk   = (const float*)d_in[3];
    const float* Wv   = (const float*)d_in[5];
    const float* bv   = (const float*)d_in[6];
    const float* Wo   = (const float*)d_in[7];
    const float* bo   = (const float*)d_in[8];
    const float* ln1g = (const float*)d_in[9];
    const float* ln1b = (const float*)d_in[10];
    const float* W1   = (const float*)d_in[11];
    const float* b1   = (const float*)d_in[12];
    const float* W2   = (const float*)d_in[13];
    const float* b2   = (const float*)d_in[14];
    const float* ln2g = (const float*)d_in[15];
    const float* ln2b = (const float*)d_in[16];
    const float* gc   = (const float*)d_in[17];
    const float* gcb  = (const float*)d_in[18];
    const float* s0v  = (const float*)d_in[19];
    const float* s1v  = (const float*)d_in[20];
    const int*   s0r  = (const int*)d_in[21];
    const int*   s0c  = (const int*)d_in[22];
    const int*   s1r  = (const int*)d_in[23];
    const int*   s1c  = (const int*)d_in[24];
    const int nnz  = in_sizes[19];
    const int BN   = in_sizes[0] / (SEQ_T * DM);   // 10400
    const int Bsz  = BN / N_SENSORS;               // 32
    const int Mtot = BN * SEQ_T;                   // 124800

    char* ws = (char*)d_ws;
    size_t off = 0;
    auto alloc = [&](size_t bytes) {
        char* r = ws + off;
        off = (off + bytes + 255) & ~(size_t)255;
        return r;
    };

    int*   offs  = (int*)alloc((size_t)2 * (N_SENSORS + 1) * 4);
    int*   ccols = (int*)alloc((size_t)2 * nnz * 4);
    float* cvals = (float*)alloc((size_t)2 * nnz * 4);
    __hip_bfloat16* Bfold  = (__hip_bfloat16*)alloc((size_t)2048 * 128 * 2);
    float* biasU = (float*)alloc(1024 * 4);
    float* beff  = (float*)alloc(128 * 4);
    __hip_bfloat16* W1_t   = (__hip_bfloat16*)alloc((size_t)65536 * 2);
    __hip_bfloat16* W2_t   = (__hip_bfloat16*)alloc((size_t)65536 * 2);
    __hip_bfloat16* Gcat_t = (__hip_bfloat16*)alloc((size_t)49152 * 2);
    __hip_bfloat16* y1 = (__hip_bfloat16*)alloc((size_t)Mtot * 128 * 2);   // 32 MB
    __hip_bfloat16* z  = (__hip_bfloat16*)alloc((size_t)Mtot * 128 * 2);   // 32 MB

    // x1/x2 b-striped from remaining ws
    const size_t perb = (size_t)3900 * 128 * 2;    // ~0.95 MB
    size_t rem = (ws_size > off) ? (ws_size - off) : 0;
    int bs = (int)(rem / (2 * perb + 8192));
    if (bs < 1) bs = 1;
    if (bs > Bsz) bs = Bsz;
    __hip_bfloat16* x1 = (__hip_bfloat16*)alloc((size_t)bs * perb);
    __hip_bfloat16* x2 = (__hip_bfloat16*)alloc((size_t)bs * perb);

    // h1 lives in d_out (dead until final GEMM overwrites it)
    __hip_bfloat16* h1 = (__hip_bfloat16*)d_out;
    int h1rows = (int)(((size_t)out_size * 4) / 1024);
    h1rows &= ~127;
    if (h1rows > Mtot) h1rows = Mtot;
    // balance stripes: use equal stripes of <= h1rows
    int nstripes = (Mtot + h1rows - 1) / h1rows;
    int stripe = ((Mtot / nstripes) + 127) & ~127;

    hipLaunchKernelGGL(build_csr_kernel, dim3(2), dim3(256), 0, stream,
                       s0v, s0r, s0c, s1v, s1r, s1c, nnz, offs, ccols, cvals);
    hipLaunchKernelGGL(prep_misc_kernel, dim3(709), dim3(256), 0, stream,
                       W1, W2, gc, Wk, bq, bo, bv, Wo, W1_t, W2_t, Gcat_t, biasU, beff);
    hipLaunchKernelGGL(fold_kernel, dim3(1024), dim3(256), 0, stream,
                       Wq, Wk, Wv, Wo, Bfold);

    hipLaunchKernelGGL(attn_fused_kernel, dim3(Mtot / 96), dim3(256), 0, stream,
                       x, Bfold, biasU, beff, ln1g, ln1b, y1);

    for (int s0 = 0; s0 < Mtot; s0 += stripe) {
        int rows = (stripe < Mtot - s0) ? stripe : (Mtot - s0);
        hipLaunchKernelGGL(HIP_KERNEL_NAME(gemm_kernel<2>), dim3(rows / 128, 4), dim3(256), 0, stream,
                           y1 + (size_t)s0 * 128, nullptr, nullptr, 128,
                           W1_t, 128, 128, h1, 512,
                           (float*)nullptr, 1 << 30, 0,
                           b1, (const __hip_bfloat16*)nullptr,
                           (const float*)nullptr, (const float*)nullptr);
        hipLaunchKernelGGL(HIP_KERNEL_NAME(gemm_kernel<3>), dim3(rows / 128, 1), dim3(256), 0, stream,
                           h1, nullptr, nullptr, 512,
                           W2_t, 512, 512, z, 128,
                           (float*)nullptr, 1 << 30, s0,
                           b2, y1 + (size_t)s0 * 128, ln2g, ln2b);
    }

    for (int b0 = 0; b0 < Bsz; b0 += bs) {
        int bsc = (bs < Bsz - b0) ? bs : (Bsz - b0);
        int rows = bsc * 3900;
        hipLaunchKernelGGL(combine_kernel, dim3(bsc * 12, 5), dim3(256), 0, stream,
                           z, offs, ccols, cvals, nnz, x1, x2, b0 * 12);
        hipLaunchKernelGGL(HIP_KERNEL_NAME(gemm_kernel<5>), dim3((rows + 127) / 128, 1), dim3(256), 0, stream,
                           z + (size_t)b0 * 3900 * 128, x1, x2, 128,
                           Gcat_t, 384, 384, (__hip_bfloat16*)nullptr, 0,
                           (float*)d_out, rows, b0 * 3900,
                           gcb, (const __hip_bfloat16*)nullptr,
                           (const float*)nullptr, (const float*)nullptr);
    }
}

// Round 7
// 768.344 us; speedup vs baseline: 6.0145x; 1.3969x over previous
//
#include <hip/hip_runtime.h>
#include <hip/hip_bf16.h>

#define N_SENSORS 325
#define SEQ_T 12
#define DM 128
#define NHEADS 8
#define DFF 512

typedef __attribute__((ext_vector_type(8))) short bf16x8;
typedef __attribute__((ext_vector_type(4))) float f32x4;

__device__ __forceinline__ float bfbits2f(short s) {
    return __uint_as_float(((unsigned)(unsigned short)s) << 16);
}
__device__ __forceinline__ short f2bfbits(float f) {
    __hip_bfloat16 h = __float2bfloat16(f);
    return *(short*)&h;
}
__device__ __forceinline__ unsigned pk2(float a, float b) {
    return (unsigned)(unsigned short)f2bfbits(a) |
           ((unsigned)(unsigned short)f2bfbits(b) << 16);
}
__device__ __forceinline__ void gload_lds16(const void* g, void* l) {
    __builtin_amdgcn_global_load_lds((const __attribute__((address_space(1))) void*)g,
                                     (__attribute__((address_space(3))) void*)l, 16, 0, 0);
}

// ---------------------------------------------------------------------------
// Dense support build: zero f32 [2][384][384] -> COO atomic scatter -> bf16.
// ---------------------------------------------------------------------------
__global__ __launch_bounds__(256) void zero_dense_kernel(float* __restrict__ Sf)
{
    int i = blockIdx.x * 256 + threadIdx.x;     // 73728 float4s
    ((f32x4*)Sf)[i] = (f32x4){0.f, 0.f, 0.f, 0.f};
}

__global__ __launch_bounds__(256) void scatter_dense_kernel(
    const float* __restrict__ s0v, const int* __restrict__ s0r, const int* __restrict__ s0c,
    const float* __restrict__ s1v, const int* __restrict__ s1r, const int* __restrict__ s1c,
    int nnz, float* __restrict__ Sf)
{
    int id = blockIdx.x * 256 + threadIdx.x;
    if (id >= 2 * nnz) return;
    int sup = id / nnz, e = id - sup * nnz;
    int r = sup ? s1r[e] : s0r[e];
    int c = sup ? s1c[e] : s0c[e];
    float v = sup ? s1v[e] : s0v[e];
    atomicAdd(&Sf[(size_t)sup * 147456 + r * 384 + c], v);
}

__global__ __launch_bounds__(256) void cast_dense_kernel(
    const float* __restrict__ Sf, __hip_bfloat16* __restrict__ Sd)
{
    int i = blockIdx.x * 256 + threadIdx.x;     // 73728 groups of 4
    f32x4 v = ((const f32x4*)Sf)[i];
    unsigned two[2] = { pk2(v[0], v[1]), pk2(v[2], v[3]) };
    ((unsigned long long*)Sd)[i] = *(unsigned long long*)two;
}

// ---------------------------------------------------------------------------
// prep: W1_t[f][d], W2_t[d][f], Gcat_t[dd][mtx*128+k], biasU (u), beff.
// ---------------------------------------------------------------------------
__global__ __launch_bounds__(256) void prep_misc_kernel(
    const float* __restrict__ W1, const float* __restrict__ W2,
    const float* __restrict__ gc, const float* __restrict__ Wk,
    const float* __restrict__ bq, const float* __restrict__ bo,
    const float* __restrict__ bv, const float* __restrict__ Wo,
    __hip_bfloat16* __restrict__ W1_t, __hip_bfloat16* __restrict__ W2_t,
    __hip_bfloat16* __restrict__ Gcat_t,
    float* __restrict__ biasU, float* __restrict__ beff)
{
    int id = blockIdx.x * 256 + threadIdx.x;   // 181376 items
    if (id < 65536) {
        int f = id >> 7, d = id & 127;
        W1_t[id] = __float2bfloat16(W1[d * 512 + f]);
    } else if (id < 131072) {
        int t = id - 65536;
        int d = t >> 9, f = t & 511;
        W2_t[t] = __float2bfloat16(W2[f * 128 + d]);
    } else if (id < 180224) {
        int t = id - 131072;
        int dd = t / 384, rem = t - dd * 384;
        int mtx = rem >> 7, kd = rem & 127;
        Gcat_t[t] = __float2bfloat16(gc[(kd * 3 + mtx) * 128 + dd]);
    } else if (id < 181248) {
        int t = id - 180224;                    // u: h*128+dd
        int h = t >> 7, dd = t & 127;
        float a = 0.f;
        for (int c = 0; c < 128; ++c) a += Wk[dd * 1024 + h * 128 + c] * bq[h * 128 + c];
        biasU[t] = a * 0.08838834764831845f;
    } else if (id < 181376) {
        int d = id - 181248;
        float a = bo[d];
        for (int h = 0; h < 8; ++h)
            for (int c = 0; c < 128; ++c)
                a += bv[h * 128 + c] * Wo[h * 16384 + c * 128 + d];
        beff[d] = a;
    }
}

// ---------------------------------------------------------------------------
// Bfold[n][k] (2048x128): n<1024: (WqWk^T)^T scaled; n>=1024: (WvWo)^T.
// ---------------------------------------------------------------------------
__global__ __launch_bounds__(256) void fold_kernel(
    const float* __restrict__ Wq, const float* __restrict__ Wk,
    const float* __restrict__ Wv, const float* __restrict__ Wo,
    __hip_bfloat16* __restrict__ Bfold)
{
    int id = blockIdx.x * 256 + threadIdx.x;   // 262144
    int n = id >> 7, k = id & 127;
    float a = 0.f;
    if (n < 1024) {
        int h = n >> 7, dd = n & 127;
        const float* wq = Wq + k * 1024 + h * 128;
        const float* wk = Wk + dd * 1024 + h * 128;
        for (int c = 0; c < 128; ++c) a += wq[c] * wk[c];
        a *= 0.08838834764831845f;
    } else {
        int h = (n >> 7) & 7, dd = n & 127;
        const float* wv = Wv + k * 1024 + h * 128;
        const float* wo = Wo + h * 16384 + dd;
        for (int c = 0; c < 128; ++c) a += wv[c] * wo[c * 128];
    }
    Bfold[id] = __float2bfloat16(a);
}

// ---------------------------------------------------------------------------
// attn v2 (proven round 6): 96 rows (8 bn) per block; all dense on MFMA.
// ---------------------------------------------------------------------------
__global__ __launch_bounds__(256) void attn_fused_kernel(
    const float* __restrict__ x,
    const __hip_bfloat16* __restrict__ Bfold,
    const float* __restrict__ biasU,
    const float* __restrict__ beff,
    const float* __restrict__ ln1g, const float* __restrict__ ln1b,
    __hip_bfloat16* __restrict__ y1)
{
    __shared__ __align__(16) char s_x[24576];    // [96][128] bf16 swizzled
    __shared__ __align__(16) char s_yut[26624];  // Y swz [96][128] / U^T [128][104]
    __shared__ __align__(16) char s_p[19968];    // P~ bf16 [96][104]
    __shared__ float s_s[96][16];
    __shared__ float s_stats[96][4][2];

    const int tid = threadIdx.x;
    const int w = tid >> 6, lane = tid & 63;
    const int l15 = lane & 15, g4 = lane >> 4;
    const size_t m0 = (size_t)blockIdx.x * 96;

    {
        const float4* xg = (const float4*)(x + m0 * 128);
#pragma unroll
        for (int i = 0; i < 12; ++i) {
            int fi = i * 256 + tid;
            int row = fi >> 5;
            int d0 = (fi & 31) * 4;
            float4 v = xg[fi];
            int base = row * 256 + (((d0 >> 3) ^ (row & 7)) << 4) + (d0 & 7) * 2;
            *(unsigned*)(s_x + base)     = pk2(v.x, v.y);
            *(unsigned*)(s_x + base + 4) = pk2(v.z, v.w);
        }
    }
    for (int i = tid; i < 1248; i += 256) *(f32x4*)(s_p + i * 16) = (f32x4){0, 0, 0, 0};

    f32x4 accO[6][2];
#pragma unroll
    for (int fm = 0; fm < 6; ++fm)
#pragma unroll
        for (int fn = 0; fn < 2; ++fn) accO[fm][fn] = (f32x4){0, 0, 0, 0};
    __syncthreads();

    for (int h = 0; h < NHEADS; ++h) {
        {
            f32x4 acc[6][2];
#pragma unroll
            for (int fn = 0; fn < 2; ++fn) {
                float b = biasU[h * 128 + w * 32 + fn * 16 + l15];
#pragma unroll
                for (int fm = 0; fm < 6; ++fm) acc[fm][fn] = (f32x4){b, b, b, b};
            }
            const char* Bp = (const char*)(Bfold + (size_t)(h * 128 + w * 32) * 128);
#pragma unroll
            for (int ks = 0; ks < 4; ++ks) {
                bf16x8 af[6], bfr[2];
#pragma unroll
                for (int fm = 0; fm < 6; ++fm) {
                    int row = fm * 16 + l15;
                    af[fm] = *(const bf16x8*)(s_x + row * 256 + (((ks * 4 + g4) ^ (row & 7)) << 4));
                }
#pragma unroll
                for (int fn = 0; fn < 2; ++fn)
                    bfr[fn] = *(const bf16x8*)(Bp + ((size_t)(fn * 16 + l15) * 128 + (ks * 4 + g4) * 8) * 2);
#pragma unroll
                for (int fm = 0; fm < 6; ++fm)
#pragma unroll
                    for (int fn = 0; fn < 2; ++fn)
                        acc[fm][fn] = __builtin_amdgcn_mfma_f32_16x16x32_bf16(
                            af[fm], bfr[fn], acc[fm][fn], 0, 0, 0);
            }
#pragma unroll
            for (int fm = 0; fm < 6; ++fm)
#pragma unroll
                for (int fn = 0; fn < 2; ++fn)
#pragma unroll
                    for (int reg = 0; reg < 4; ++reg) {
                        int row = fm * 16 + g4 * 4 + reg;
                        int col = w * 32 + fn * 16 + l15;
                        *(short*)(s_yut + row * 256 + (((col >> 3) ^ (row & 7)) << 4) + (col & 7) * 2)
                            = f2bfbits(acc[fm][fn][reg]);
                    }
        }
        __syncthreads();   // bar1

#pragma unroll
        for (int q = 0; q < 4; ++q) {
            int tt = w + q * 4;
            int ti, tj;
            if (tt < 6)       { ti = tt;      tj = tt; }
            else if (tt < 11) { ti = tt - 6;  tj = tt - 5; }
            else              { ti = tt - 10; tj = tt - 11; }
            f32x4 sa = (f32x4){0, 0, 0, 0};
#pragma unroll
            for (int ks = 0; ks < 4; ++ks) {
                int ra = ti * 16 + l15;
                int rb = tj * 16 + l15;
                bf16x8 af = *(const bf16x8*)(s_yut + ra * 256 + (((ks * 4 + g4) ^ (ra & 7)) << 4));
                bf16x8 bf = *(const bf16x8*)(s_x   + rb * 256 + (((ks * 4 + g4) ^ (rb & 7)) << 4));
                sa = __builtin_amdgcn_mfma_f32_16x16x32_bf16(af, bf, sa, 0, 0, 0);
            }
#pragma unroll
            for (int reg = 0; reg < 4; ++reg) {
                int r = ti * 16 + g4 * 4 + reg;
                int c = tj * 16 + l15;
                if (r / 12 == c / 12) s_s[r][c - (c / 12) * 12] = sa[reg];
            }
        }
        __syncthreads();   // bar2

        if (tid < 96) {
            int row = tid, bnl = row / 12;
            float m = -1e30f;
#pragma unroll
            for (int s2 = 0; s2 < 12; ++s2) m = fmaxf(m, s_s[row][s2]);
            float e[12], sum = 0.f;
#pragma unroll
            for (int s2 = 0; s2 < 12; ++s2) { e[s2] = __expf(s_s[row][s2] - m); sum += e[s2]; }
            float inv = 1.f / sum;
#pragma unroll
            for (int jj = 0; jj < 6; ++jj)
                *(unsigned*)(s_p + row * 208 + bnl * 24 + jj * 4) =
                    pk2(e[2 * jj] * inv, e[2 * jj + 1] * inv);
        }

        {
            f32x4 acc[6][2];
#pragma unroll
            for (int fm = 0; fm < 6; ++fm)
#pragma unroll
                for (int fn = 0; fn < 2; ++fn) acc[fm][fn] = (f32x4){0, 0, 0, 0};
            const char* Bp = (const char*)(Bfold + (size_t)(1024 + h * 128 + w * 32) * 128);
#pragma unroll
            for (int ks = 0; ks < 4; ++ks) {
                bf16x8 af[6], bfr[2];
#pragma unroll
                for (int fm = 0; fm < 6; ++fm) {
                    int row = fm * 16 + l15;
                    af[fm] = *(const bf16x8*)(s_x + row * 256 + (((ks * 4 + g4) ^ (row & 7)) << 4));
                }
#pragma unroll
                for (int fn = 0; fn < 2; ++fn)
                    bfr[fn] = *(const bf16x8*)(Bp + ((size_t)(fn * 16 + l15) * 128 + (ks * 4 + g4) * 8) * 2);
#pragma unroll
                for (int fm = 0; fm < 6; ++fm)
#pragma unroll
                    for (int fn = 0; fn < 2; ++fn)
                        acc[fm][fn] = __builtin_amdgcn_mfma_f32_16x16x32_bf16(
                            af[fm], bfr[fn], acc[fm][fn], 0, 0, 0);
            }
            __syncthreads();
#pragma unroll
            for (int fm = 0; fm < 6; ++fm)
#pragma unroll
                for (int fn = 0; fn < 2; ++fn) {
                    int d = w * 32 + fn * 16 + l15;
                    int s0 = fm * 16 + g4 * 4;
                    *(unsigned*)(s_yut + d * 208 + s0 * 2)     = pk2(acc[fm][fn][0], acc[fm][fn][1]);
                    *(unsigned*)(s_yut + d * 208 + s0 * 2 + 4) = pk2(acc[fm][fn][2], acc[fm][fn][3]);
                }
        }
        __syncthreads();   // bar3

#pragma unroll
        for (int ks = 0; ks < 3; ++ks) {
            bf16x8 af[6], bfr[2];
#pragma unroll
            for (int fm = 0; fm < 6; ++fm)
                af[fm] = *(const bf16x8*)(s_p + (fm * 16 + l15) * 208 + (ks * 4 + g4) * 16);
#pragma unroll
            for (int fn = 0; fn < 2; ++fn)
                bfr[fn] = *(const bf16x8*)(s_yut + (w * 32 + fn * 16 + l15) * 208 + (ks * 4 + g4) * 16);
#pragma unroll
            for (int fm = 0; fm < 6; ++fm)
#pragma unroll
                for (int fn = 0; fn < 2; ++fn)
                    accO[fm][fn] = __builtin_amdgcn_mfma_f32_16x16x32_bf16(
                        af[fm], bfr[fn], accO[fm][fn], 0, 0, 0);
        }
        __syncthreads();   // bar4
    }

#pragma unroll
    for (int fm = 0; fm < 6; ++fm)
#pragma unroll
        for (int reg = 0; reg < 4; ++reg) {
            int row = fm * 16 + g4 * 4 + reg;
            float s1 = 0.f, s2 = 0.f;
#pragma unroll
            for (int fn = 0; fn < 2; ++fn) {
                int col = w * 32 + fn * 16 + l15;
                float xr = bfbits2f(*(const short*)(s_x + row * 256 +
                             (((col >> 3) ^ (row & 7)) << 4) + (col & 7) * 2));
                float v = accO[fm][fn][reg] + beff[col] + xr;
                accO[fm][fn][reg] = v;
                s1 += v; s2 += v * v;
            }
#pragma unroll
            for (int o = 1; o < 16; o <<= 1) { s1 += __shfl_xor(s1, o); s2 += __shfl_xor(s2, o); }
            if (l15 == 0) { s_stats[row][w][0] = s1; s_stats[row][w][1] = s2; }
        }
    __syncthreads();
#pragma unroll
    for (int fm = 0; fm < 6; ++fm)
#pragma unroll
        for (int reg = 0; reg < 4; ++reg) {
            int row = fm * 16 + g4 * 4 + reg;
            float S1 = s_stats[row][0][0] + s_stats[row][1][0] + s_stats[row][2][0] + s_stats[row][3][0];
            float S2 = s_stats[row][0][1] + s_stats[row][1][1] + s_stats[row][2][1] + s_stats[row][3][1];
            float mu = S1 * (1.f / 128.f);
            float rs = rsqrtf(S2 * (1.f / 128.f) - mu * mu + 1e-3f);
#pragma unroll
            for (int fn = 0; fn < 2; ++fn) {
                int col = w * 32 + fn * 16 + l15;
                float y = (accO[fm][fn][reg] - mu) * rs * ln1g[col] + ln1b[col];
                *(short*)(s_yut + row * 256 + col * 2) = f2bfbits(y);
            }
        }
    __syncthreads();
#pragma unroll
    for (int i = 0; i < 6; ++i) {
        int idx = i * 256 + tid;
        int row = idx >> 4, slot = idx & 15;
        *(float4*)((char*)y1 + (m0 + row) * 256 + slot * 16) =
            *(const float4*)(s_yut + idx * 16);
    }
}

// ---------------------------------------------------------------------------
// MFMA GEMM, 128x128 tile. EPI:
//   2 = FFN1: +b1, relu -> bf16 C (stride 512)
//   3 = FFN2: +b2 +resid(y1) + LN2 -> z bf16, rows scattered (b,n,t)->(b,t,n)
//   5 = MGCN: A chunks {A,A1,A2}, +gcb -> f32 d_out rows (b,t,n)->(b,n,t)
// ---------------------------------------------------------------------------
template <int EPI>
__global__ __launch_bounds__(256) void gemm_kernel(
    const __hip_bfloat16* __restrict__ A, const __hip_bfloat16* __restrict__ A1,
    const __hip_bfloat16* __restrict__ A2, int Astride,
    const __hip_bfloat16* __restrict__ Bw, int Bstride, int Ktot,
    __hip_bfloat16* __restrict__ C, int Cstride,
    float* __restrict__ outF, int Mloc, int m0base,
    const float* __restrict__ bias,
    const __hip_bfloat16* __restrict__ resid,
    const float* __restrict__ lng, const float* __restrict__ lnb)
{
    __shared__ __align__(16) char s_lds[65536];
    __hip_bfloat16* Alds = (__hip_bfloat16*)s_lds;
    __hip_bfloat16* Blds = (__hip_bfloat16*)(s_lds + 32768);
    const int tid = threadIdx.x;
    const int w = tid >> 6, lane = tid & 63;
    const int l15 = lane & 15, g4 = lane >> 4;
    const int m0 = blockIdx.x * 128;
    const int n0 = blockIdx.y * 128;

    f32x4 acc[2][8];
#pragma unroll
    for (int a = 0; a < 2; ++a)
#pragma unroll
        for (int b = 0; b < 8; ++b) acc[a][b] = (f32x4){0.f, 0.f, 0.f, 0.f};

    const int nchunks = Ktot >> 7;
    for (int kc = 0; kc < nchunks; ++kc) {
        const __hip_bfloat16* Asel = A;
        size_t koff = (size_t)kc * 128;
        if (EPI == 5) { Asel = (kc == 0) ? A : (kc == 1 ? A1 : A2); koff = 0; }
#pragma unroll
        for (int i = 0; i < 8; ++i) {
            int fs = (w * 8 + i) * 64 + lane;
            int row = fs >> 4, slot = fs & 15;
            int sw = (slot ^ (row & 7)) << 4;
            int rowA = m0 + row;
            if (EPI == 5) rowA = min(rowA, Mloc - 1);
            gload_lds16((const char*)Asel + ((size_t)rowA * Astride + koff) * 2 + sw,
                        (char*)Alds + (size_t)(w * 8 + i) * 1024);
            gload_lds16((const char*)Bw + ((size_t)(n0 + row) * Bstride + (size_t)kc * 128) * 2 + sw,
                        (char*)Blds + (size_t)(w * 8 + i) * 1024);
        }
        __syncthreads();
        const char* Ab = (const char*)Alds;
        const char* Bb = (const char*)Blds;
#pragma unroll
        for (int ks = 0; ks < 4; ++ks) {
            bf16x8 af[2], bfr[8];
#pragma unroll
            for (int fm = 0; fm < 2; ++fm) {
                int row = w * 32 + fm * 16 + l15;
                int c = (ks * 4 + g4) ^ (row & 7);
                af[fm] = *(const bf16x8*)(Ab + row * 256 + c * 16);
            }
#pragma unroll
            for (int fn = 0; fn < 8; ++fn) {
                int row = fn * 16 + l15;
                int c = (ks * 4 + g4) ^ (row & 7);
                bfr[fn] = *(const bf16x8*)(Bb + row * 256 + c * 16);
            }
#pragma unroll
            for (int fm = 0; fm < 2; ++fm)
#pragma unroll
                for (int fn = 0; fn < 8; ++fn)
                    acc[fm][fn] = __builtin_amdgcn_mfma_f32_16x16x32_bf16(
                        af[fm], bfr[fn], acc[fm][fn], 0, 0, 0);
        }
        __syncthreads();
    }

    if (EPI == 2) {
        __hip_bfloat16* Clds = Alds;
#pragma unroll
        for (int fm = 0; fm < 2; ++fm)
#pragma unroll
            for (int reg = 0; reg < 4; ++reg) {
                int mlt = w * 32 + fm * 16 + g4 * 4 + reg;
#pragma unroll
                for (int fn = 0; fn < 8; ++fn) {
                    int nl = fn * 16 + l15;
                    float v = acc[fm][fn][reg] + bias[n0 + nl];
                    Clds[mlt * 128 + nl] = __float2bfloat16(fmaxf(v, 0.f));
                }
            }
        __syncthreads();
#pragma unroll
        for (int i = 0; i < 8; ++i) {
            int fs = i * 256 + tid;
            int row = fs >> 4, slot = fs & 15;
            *(float4*)((char*)C + ((size_t)(m0 + row) * Cstride + n0) * 2 + (size_t)slot * 16) =
                *(const float4*)((const char*)Clds + (size_t)fs * 16);
        }
    } else if (EPI == 3) {
        __hip_bfloat16* Clds = Alds;
#pragma unroll
        for (int fm = 0; fm < 2; ++fm)
#pragma unroll
            for (int reg = 0; reg < 4; ++reg) {
                int mlt = w * 32 + fm * 16 + g4 * 4 + reg;
                float v[8], s1 = 0.f, s2 = 0.f;
#pragma unroll
                for (int fn = 0; fn < 8; ++fn) {
                    int nl = fn * 16 + l15;
                    float t = acc[fm][fn][reg] + bias[nl]
                            + bfbits2f(((const short*)resid)[(size_t)(m0 + mlt) * 128 + nl]);
                    v[fn] = t; s1 += t; s2 += t * t;
                }
#pragma unroll
                for (int o = 1; o < 16; o <<= 1) { s1 += __shfl_xor(s1, o); s2 += __shfl_xor(s2, o); }
                float mu = s1 * (1.f / 128.f);
                float rstd = rsqrtf(s2 * (1.f / 128.f) - mu * mu + 1e-3f);
#pragma unroll
                for (int fn = 0; fn < 8; ++fn) {
                    int nl = fn * 16 + l15;
                    Clds[mlt * 128 + nl] = __float2bfloat16((v[fn] - mu) * rstd * lng[nl] + lnb[nl]);
                }
            }
        __syncthreads();
#pragma unroll
        for (int i = 0; i < 8; ++i) {
            int fs = i * 256 + tid;
            int row = fs >> 4, slot = fs & 15;
            int m_g = m0base + m0 + row;
            int bn = m_g / 12, t = m_g - bn * 12;
            int b = bn / N_SENSORS, ns = bn - b * N_SENSORS;
            size_t zrow = (size_t)(b * 12 + t) * N_SENSORS + ns;
            *(float4*)((char*)C + zrow * 256 + (size_t)slot * 16) =
                *(const float4*)((const char*)Alds + (size_t)fs * 16);
        }
    } else {  // EPI == 5
        float* Cf = (float*)s_lds;
#pragma unroll
        for (int fm = 0; fm < 2; ++fm)
#pragma unroll
            for (int reg = 0; reg < 4; ++reg) {
                int mlt = w * 32 + fm * 16 + g4 * 4 + reg;
#pragma unroll
                for (int fn = 0; fn < 8; ++fn) {
                    int nl = fn * 16 + l15;
                    Cf[mlt * 128 + nl] = acc[fm][fn][reg] + bias[nl];
                }
            }
        __syncthreads();
#pragma unroll
        for (int i = 0; i < 16; ++i) {
            int fs = i * 256 + tid;
            int row = fs >> 5, slot = fs & 31;
            if (m0 + row < Mloc) {
                int mg = m0base + m0 + row;        // (b,t,n) order
                int b = mg / 3900, r = mg - b * 3900;
                int t = r / N_SENSORS, n = r - t * N_SENSORS;
                size_t orow = (size_t)(b * N_SENSORS + n) * 12 + t;
                *(float4*)(outF + orow * 128 + slot * 4) =
                    *(const float4*)(s_lds + (size_t)fs * 16);
            }
        }
    }
}

// ---------------------------------------------------------------------------
// transpose z (b,t,n,d) -> z_T stripe [lbt][128 d][384 c] bf16, zero-padded c.
// ---------------------------------------------------------------------------
__global__ __launch_bounds__(256) void transpose_z_kernel(
    const __hip_bfloat16* __restrict__ z, int gbt0,
    __hip_bfloat16* __restrict__ zT)
{
    __shared__ short tile[64][136];
    const int lbt = blockIdx.x;
    const int tid = threadIdx.x;
    const short* zb = (const short*)z + (size_t)(gbt0 + lbt) * (N_SENSORS * 128);
    short* zo = (short*)zT + (size_t)lbt * 49152;
    for (int c0 = 0; c0 < 384; c0 += 64) {
        __syncthreads();
#pragma unroll
        for (int i = 0; i < 4; ++i) {
            int ch = i * 256 + tid;          // 1024 16B chunks
            int r = ch >> 4, dc = ch & 15;
            int n = c0 + r;
            bf16x8 v = (bf16x8){0, 0, 0, 0, 0, 0, 0, 0};
            if (n < N_SENSORS) v = *(const bf16x8*)(zb + (size_t)n * 128 + dc * 8);
#pragma unroll
            for (int j = 0; j < 8; ++j) tile[r][dc * 8 + j] = v[j];
        }
        __syncthreads();
        int d = tid >> 1, hf = tid & 1;
        short buf[32];
#pragma unroll
        for (int j = 0; j < 32; ++j) buf[j] = tile[hf * 32 + j][d];
#pragma unroll
        for (int j = 0; j < 4; ++j)
            *(bf16x8*)(zo + (size_t)d * 384 + c0 + hf * 32 + j * 8) = *(bf16x8*)&buf[j * 8];
    }
}

// ---------------------------------------------------------------------------
// spmm via dense MFMA: x_sup(n,d) = Sdense_sup @ z_T_bt.  M=128-tile, K=384,
// N=128.  grid (lbt, 6): y%3 = m-chunk, y/3 = support.
// ---------------------------------------------------------------------------
__global__ __launch_bounds__(256) void spmm_dense_kernel(
    const __hip_bfloat16* __restrict__ Sd,   // [2][384][384]
    const __hip_bfloat16* __restrict__ zT,   // stripe [lbt][128][384]
    __hip_bfloat16* __restrict__ x1, __hip_bfloat16* __restrict__ x2)
{
    __shared__ __align__(16) char s_lds[65536];
    __hip_bfloat16* Alds = (__hip_bfloat16*)s_lds;
    __hip_bfloat16* Blds = (__hip_bfloat16*)(s_lds + 32768);
    const int tid = threadIdx.x;
    const int w = tid >> 6, lane = tid & 63;
    const int l15 = lane & 15, g4 = lane >> 4;
    const int lbt = blockIdx.x;
    const int m0 = (blockIdx.y % 3) * 128;
    const int sup = blockIdx.y / 3;

    const __hip_bfloat16* A = Sd + (size_t)sup * 147456;
    const __hip_bfloat16* B = zT + (size_t)lbt * 49152;

    f32x4 acc[2][8];
#pragma unroll
    for (int a = 0; a < 2; ++a)
#pragma unroll
        for (int b = 0; b < 8; ++b) acc[a][b] = (f32x4){0.f, 0.f, 0.f, 0.f};

    for (int kc = 0; kc < 3; ++kc) {
#pragma unroll
        for (int i = 0; i < 8; ++i) {
            int fs = (w * 8 + i) * 64 + lane;
            int row = fs >> 4, slot = fs & 15;
            int sw = (slot ^ (row & 7)) << 4;
            gload_lds16((const char*)A + ((size_t)(m0 + row) * 384 + (size_t)kc * 128) * 2 + sw,
                        (char*)Alds + (size_t)(w * 8 + i) * 1024);
            gload_lds16((const char*)B + ((size_t)row * 384 + (size_t)kc * 128) * 2 + sw,
                        (char*)Blds + (size_t)(w * 8 + i) * 1024);
        }
        __syncthreads();
#pragma unroll
        for (int ks = 0; ks < 4; ++ks) {
            bf16x8 af[2], bfr[8];
#pragma unroll
            for (int fm = 0; fm < 2; ++fm) {
                int row = w * 32 + fm * 16 + l15;
                int c = (ks * 4 + g4) ^ (row & 7);
                af[fm] = *(const bf16x8*)((const char*)Alds + row * 256 + c * 16);
            }
#pragma unroll
            for (int fn = 0; fn < 8; ++fn) {
                int row = fn * 16 + l15;
                int c = (ks * 4 + g4) ^ (row & 7);
                bfr[fn] = *(const bf16x8*)((const char*)Blds + row * 256 + c * 16);
            }
#pragma unroll
            for (int fm = 0; fm < 2; ++fm)
#pragma unroll
                for (int fn = 0; fn < 8; ++fn)
                    acc[fm][fn] = __builtin_amdgcn_mfma_f32_16x16x32_bf16(
                        af[fm], bfr[fn], acc[fm][fn], 0, 0, 0);
        }
        __syncthreads();
    }

    __hip_bfloat16* Clds = Alds;
#pragma unroll
    for (int fm = 0; fm < 2; ++fm)
#pragma unroll
        for (int reg = 0; reg < 4; ++reg) {
            int mlt = w * 32 + fm * 16 + g4 * 4 + reg;
#pragma unroll
            for (int fn = 0; fn < 8; ++fn) {
                int nl = fn * 16 + l15;
                Clds[mlt * 128 + nl] = __float2bfloat16(acc[fm][fn][reg]);
            }
        }
    __syncthreads();
    __hip_bfloat16* Xo = (sup ? x2 : x1) + (size_t)lbt * (N_SENSORS * 128);
#pragma unroll
    for (int i = 0; i < 8; ++i) {
        int fs = i * 256 + tid;
        int row = fs >> 4, slot = fs & 15;
        int n = m0 + row;
        if (n < N_SENSORS)
            *(float4*)((char*)Xo + (size_t)n * 256 + (size_t)slot * 16) =
                *(const float4*)((const char*)Clds + (size_t)fs * 16);
    }
}

// ---------------------------------------------------------------------------
extern "C" void kernel_launch(void* const* d_in, const int* in_sizes, int n_in,
                              void* d_out, int out_size, void* d_ws, size_t ws_size,
                              hipStream_t stream)
{
    const float* x    = (const float*)d_in[0];
    const float* Wq   = (const float*)d_in[1];
    const float* bq   = (const float*)d_in[2];
    const float* Wk   = (const float*)d_in[3];
    const float* Wv   = (const float*)d_in[5];
    const float* bv   = (const float*)d_in[6];
    const float* Wo   = (const float*)d_in[7];
    const float* bo   = (const float*)d_in[8];
    const float* ln1g = (const float*)d_in[9];
    const float* ln1b = (const float*)d_in[10];
    const float* W1   = (const float*)d_in[11];
    const float* b1   = (const float*)d_in[12];
    const float* W2   = (const float*)d_in[13];
    const float* b2   = (const float*)d_in[14];
    const float* ln2g = (const float*)d_in[15];
    const float* ln2b = (const float*)d_in[16];
    const float* gc   = (const float*)d_in[17];
    const float* gcb  = (const float*)d_in[18];
    const float* s0v  = (const float*)d_in[19];
    const float* s1v  = (const float*)d_in[20];
    const int*   s0r  = (const int*)d_in[21];
    const int*   s0c  = (const int*)d_in[22];
    const int*   s1r  = (const int*)d_in[23];
    const int*   s1c  = (const int*)d_in[24];
    const int nnz  = in_sizes[19];
    const int BN   = in_sizes[0] / (SEQ_T * DM);   // 10400
    const int Bsz  = BN / N_SENSORS;               // 32
    const int Mtot = BN * SEQ_T;                   // 124800

    char* ws = (char*)d_ws;
    size_t off = 0;
    auto alloc = [&](size_t bytes) {
        char* r = ws + off;
        off = (off + bytes + 255) & ~(size_t)255;
        return r;
    };

    __hip_bfloat16* Bfold  = (__hip_bfloat16*)alloc((size_t)2048 * 128 * 2);
    float* biasU = (float*)alloc(1024 * 4);
    float* beff  = (float*)alloc(128 * 4);
    __hip_bfloat16* W1_t   = (__hip_bfloat16*)alloc((size_t)65536 * 2);
    __hip_bfloat16* W2_t   = (__hip_bfloat16*)alloc((size_t)65536 * 2);
    __hip_bfloat16* Gcat_t = (__hip_bfloat16*)alloc((size_t)49152 * 2);
    float*          Sf     = (float*)alloc((size_t)2 * 147456 * 4);
    __hip_bfloat16* Sd     = (__hip_bfloat16*)alloc((size_t)2 * 147456 * 2);
    __hip_bfloat16* y1 = (__hip_bfloat16*)alloc((size_t)Mtot * 128 * 2);   // 32 MB
    __hip_bfloat16* z  = (__hip_bfloat16*)alloc((size_t)Mtot * 128 * 2);   // 32 MB

    // per-b stripe buffers for MGCN: z_T + x1 + x2
    const size_t zT_perb = (size_t)12 * 49152 * 2;         // 1179648 B
    const size_t x_perb  = (size_t)12 * N_SENSORS * 128 * 2; // 998400 B
    size_t rem = (ws_size > off) ? (ws_size - off) : 0;
    int bs = (int)(rem / (zT_perb + 2 * x_perb + 8192));
    if (bs < 1) bs = 1;
    if (bs > Bsz) bs = Bsz;
    __hip_bfloat16* zT = (__hip_bfloat16*)alloc((size_t)bs * zT_perb);
    __hip_bfloat16* x1 = (__hip_bfloat16*)alloc((size_t)bs * x_perb);
    __hip_bfloat16* x2 = (__hip_bfloat16*)alloc((size_t)bs * x_perb);

    // h1 lives in d_out (dead until final GEMM overwrites it)
    __hip_bfloat16* h1 = (__hip_bfloat16*)d_out;
    int h1rows = (int)(((size_t)out_size * 4) / 1024);
    h1rows &= ~127;
    if (h1rows > Mtot) h1rows = Mtot;
    int nstripes = (Mtot + h1rows - 1) / h1rows;
    int stripe = ((Mtot / nstripes) + 127) & ~127;

    hipLaunchKernelGGL(prep_misc_kernel, dim3(709), dim3(256), 0, stream,
                       W1, W2, gc, Wk, bq, bo, bv, Wo, W1_t, W2_t, Gcat_t, biasU, beff);
    hipLaunchKernelGGL(fold_kernel, dim3(1024), dim3(256), 0, stream,
                       Wq, Wk, Wv, Wo, Bfold);
    hipLaunchKernelGGL(zero_dense_kernel, dim3(288), dim3(256), 0, stream, Sf);
    hipLaunchKernelGGL(scatter_dense_kernel, dim3((2 * nnz + 255) / 256), dim3(256), 0, stream,
                       s0v, s0r, s0c, s1v, s1r, s1c, nnz, Sf);
    hipLaunchKernelGGL(cast_dense_kernel, dim3(288), dim3(256), 0, stream, Sf, Sd);

    hipLaunchKernelGGL(attn_fused_kernel, dim3(Mtot / 96), dim3(256), 0, stream,
                       x, Bfold, biasU, beff, ln1g, ln1b, y1);

    for (int s0 = 0; s0 < Mtot; s0 += stripe) {
        int rows = (stripe < Mtot - s0) ? stripe : (Mtot - s0);
        hipLaunchKernelGGL(HIP_KERNEL_NAME(gemm_kernel<2>), dim3(rows / 128, 4), dim3(256), 0, stream,
                           y1 + (size_t)s0 * 128, nullptr, nullptr, 128,
                           W1_t, 128, 128, h1, 512,
                           (float*)nullptr, 1 << 30, 0,
                           b1, (const __hip_bfloat16*)nullptr,
                           (const float*)nullptr, (const float*)nullptr);
        hipLaunchKernelGGL(HIP_KERNEL_NAME(gemm_kernel<3>), dim3(rows / 128, 1), dim3(256), 0, stream,
                           h1, nullptr, nullptr, 512,
                           W2_t, 512, 512, z, 128,
                           (float*)nullptr, 1 << 30, s0,
                           b2, y1 + (size_t)s0 * 128, ln2g, ln2b);
    }

    for (int b0 = 0; b0 < Bsz; b0 += bs) {
        int bsc = (bs < Bsz - b0) ? bs : (Bsz - b0);
        int rows = bsc * 3900;
        hipLaunchKernelGGL(transpose_z_kernel, dim3(bsc * 12), dim3(256), 0, stream,
                           z, b0 * 12, zT);
        hipLaunchKernelGGL(spmm_dense_kernel, dim3(bsc * 12, 6), dim3(256), 0, stream,
                           Sd, zT, x1, x2);
        hipLaunchKernelGGL(HIP_KERNEL_NAME(gemm_kernel<5>), dim3((rows + 127) / 128, 1), dim3(256), 0, stream,
                           z + (size_t)b0 * 3900 * 128, x1, x2, 128,
                           Gcat_t, 384, 384, (__hip_bfloat16*)nullptr, 0,
                           (float*)d_out, rows, b0 * 3900,
                           gcb, (const __hip_bfloat16*)nullptr,
                           (const float*)nullptr, (const float*)nullptr);
    }
}